// Round 4
// baseline (2401.836 us; speedup 1.0000x reference)
//
#include <hip/hip_runtime.h>
#include <hip/hip_bf16.h>

// ---------------------------------------------------------------------------
// Full fp32 implementation of the mv3Dunet_down_text_cmsa forward pass.
// Round 4: conv3d with 2 oc/thread (higher FMA-per-LDS-read), fused tail:
// attrow = att+attv+proj+residuals in one kernel; gcn spmm+fin fused;
// ln+linear fused.
// ---------------------------------------------------------------------------

__device__ __forceinline__ float bmax256(float v, volatile float* red, int tid) {
    for (int sh = 32; sh; sh >>= 1) v = fmaxf(v, __shfl_xor(v, sh));
    __syncthreads();
    if ((tid & 63) == 0) red[tid >> 6] = v;
    __syncthreads();
    return fmaxf(fmaxf(red[0], red[1]), fmaxf(red[2], red[3]));
}
__device__ __forceinline__ float bsum256(float v, volatile float* red, int tid) {
    for (int sh = 32; sh; sh >>= 1) v += __shfl_xor(v, sh);
    __syncthreads();
    if ((tid & 63) == 0) red[tid >> 6] = v;
    __syncthreads();
    return red[0] + red[1] + red[2] + red[3];
}

// ---------------- fused transpose of 8 [196,196] matrices ----------------
struct P8 { const float* p[8]; };
__global__ void k_transpose8(P8 ws_in, float* __restrict__ wt) {
    int i = blockIdx.x, m = blockIdx.y;
    const float* w = ws_in.p[m];
    float* o = wt + (size_t)m * 38416;
    for (int t = threadIdx.x; t < 196; t += blockDim.x)
        o[(size_t)i * 196 + t] = w[(size_t)t * 196 + i];
}

// ---------------- 3x3x3 'same' conv, 2 oc per thread ----------------
// Thread = (ol 0..31, h 0..6); handles oc = o0+ol and o0+ol+32.
// Grid = (OC/64, G, B). Partial sums over input-channel groups.
#define CCH 4
__global__ __launch_bounds__(256, 2) void k_conv3d_v3(
    const float* __restrict__ x, const float* __restrict__ w,
    float* __restrict__ part, int IC, int icg, int OC) {
    __shared__ float xs[CCH][6][9][12];   // zero-padded input tile (10.1 KB)
    __shared__ float wsh[64][116];        // [oo][cc*28+k]; stride 116: aligned + bank-spread
    const int tid = threadIdx.x;
    const int o0 = blockIdx.x * 64, g = blockIdx.y, b = blockIdx.z;
    const int cbase = g * icg;

    for (int i = tid; i < CCH * 648; i += 256) ((float*)xs)[i] = 0.f;

    const int ol = tid / 7;
    const int h = tid - ol * 7;
    const bool active = tid < 224;

    float acc[2][4][7];
#pragma unroll
    for (int p = 0; p < 2; ++p)
#pragma unroll
        for (int d = 0; d < 4; ++d)
#pragma unroll
            for (int i = 0; i < 7; ++i) acc[p][d][i] = 0.f;

    for (int c0 = 0; c0 < icg; c0 += CCH) {
        __syncthreads();
        for (int i = tid; i < CCH * 196; i += 256) {
            int cc = i / 196, ss = i - cc * 196;
            int dd = ss / 49, rr = ss - dd * 49;
            int hh = rr / 7, ww = rr - hh * 7;
            xs[cc][dd + 1][hh + 1][ww + 1] =
                x[(size_t)(b * IC + cbase + c0 + cc) * 196 + ss];
        }
        for (int i = tid; i < 64 * CCH * 27; i += 256) {
            int oo = i / (CCH * 27);
            int r = i - oo * CCH * 27;
            int cc = r / 27, k = r - cc * 27;
            wsh[oo][cc * 28 + k] =
                w[(size_t)((o0 + oo) * IC + cbase + c0 + cc) * 27 + k];
        }
        __syncthreads();
        if (!active) continue;
        for (int cc = 0; cc < CCH; ++cc) {
            float wA[27], wB[27];
#pragma unroll
            for (int k = 0; k < 27; ++k) wA[k] = wsh[ol][cc * 28 + k];
#pragma unroll
            for (int k = 0; k < 27; ++k) wB[k] = wsh[ol + 32][cc * 28 + k];
#pragma unroll
            for (int pd = 0; pd < 6; ++pd) {
#pragma unroll
                for (int ph = 0; ph < 3; ++ph) {
                    const float* row = &xs[cc][pd][h + ph][0];
                    float r[9];
#pragma unroll
                    for (int k = 0; k < 9; ++k) r[k] = row[k];
#pragma unroll
                    for (int kd = 0; kd < 3; ++kd) {
                        int d = pd - kd;
                        if (d >= 0 && d < 4) {
                            float w0a = wA[kd * 9 + ph * 3 + 0];
                            float w1a = wA[kd * 9 + ph * 3 + 1];
                            float w2a = wA[kd * 9 + ph * 3 + 2];
                            float w0b = wB[kd * 9 + ph * 3 + 0];
                            float w1b = wB[kd * 9 + ph * 3 + 1];
                            float w2b = wB[kd * 9 + ph * 3 + 2];
#pragma unroll
                            for (int i = 0; i < 7; ++i) {
                                acc[0][d][i] += r[i] * w0a + r[i + 1] * w1a + r[i + 2] * w2a;
                                acc[1][d][i] += r[i] * w0b + r[i + 1] * w1b + r[i + 2] * w2b;
                            }
                        }
                    }
                }
            }
        }
    }
    if (active) {
        float* base = &part[((size_t)g * 32 + b) * OC * 196];
#pragma unroll
        for (int p = 0; p < 2; ++p) {
            float* yp = base + (size_t)(o0 + ol + p * 32) * 196 + h * 7;
#pragma unroll
            for (int d = 0; d < 4; ++d)
#pragma unroll
                for (int i = 0; i < 7; ++i) yp[d * 49 + i] = acc[p][d][i];
        }
    }
}

// sum G=8 partials
__global__ void k_reduce_part(const float* __restrict__ part, float* __restrict__ y,
                              int n) {
    int i = blockIdx.x * blockDim.x + threadIdx.x;
    if (i < n) {
        float s = 0.f;
#pragma unroll
        for (int g = 0; g < 8; ++g) s += part[(size_t)g * n + i];
        y[i] = s;
    }
}

// ---------------- BN (training mode, axes 0,2,3,4) ----------------
__global__ void k_bn_stats(const float* __restrict__ y, float* __restrict__ stats,
                           int C) {
    int ch = blockIdx.x; int tid = threadIdx.x;
    float s = 0.f, s2 = 0.f;
    for (int b = 0; b < 32; ++b) {
        const float* p = &y[(size_t)(b * C + ch) * 196];
        for (int i = tid; i < 196; i += 256) { float v = p[i]; s += v; s2 += v * v; }
    }
    __shared__ float r1[4], r2[4];
    for (int sh = 32; sh; sh >>= 1) { s += __shfl_xor(s, sh); s2 += __shfl_xor(s2, sh); }
    if ((tid & 63) == 0) { r1[tid >> 6] = s; r2[tid >> 6] = s2; }
    __syncthreads();
    if (tid == 0) {
        float S = r1[0] + r1[1] + r1[2] + r1[3];
        float S2 = r2[0] + r2[1] + r2[2] + r2[3];
        float m = S / 6272.f;
        float v = S2 / 6272.f - m * m;
        stats[2 * ch] = m;
        stats[2 * ch + 1] = rsqrtf(v + 1e-5f);
    }
}

__global__ void k_bn_apply_relu(float* __restrict__ y, const float* __restrict__ stats,
                                const float* __restrict__ g, const float* __restrict__ be,
                                int C) {
    int idx = blockIdx.x;           // b*C + ch
    int ch = idx % C;
    int s = threadIdx.x;
    if (s < 196) {
        float m = stats[2 * ch], r = stats[2 * ch + 1];
        float v = y[(size_t)idx * 196 + s];
        y[(size_t)idx * 196 + s] = fmaxf((v - m) * r * g[ch] + be[ch], 0.f);
    }
}

// ---------------- catnum: Linear(A->196) + BN over batch + SiLU -------------
__global__ void k_catnum(const float* __restrict__ inp, int A,
                         const float* __restrict__ w, const float* __restrict__ bias,
                         const float* __restrict__ g, const float* __restrict__ be,
                         float* __restrict__ outv) {
    int j = blockIdx.x;             // feature 0..195
    int lane = threadIdx.x;         // 64 threads, 32 active
    float v = 0.f;
    if (lane < 32) {
        v = bias[j];
        for (int k = 0; k < A; ++k) v += inp[lane * A + k] * w[j * A + k];
    }
    float s = (lane < 32) ? v : 0.f;
    float s2 = (lane < 32) ? v * v : 0.f;
    for (int m = 16; m; m >>= 1) { s += __shfl_xor(s, m, 32); s2 += __shfl_xor(s2, m, 32); }
    if (lane < 32) {
        float mean = s / 32.f;
        float var = s2 / 32.f - mean * mean;
        float rstd = rsqrtf(var + 1e-5f);
        float t = (v - mean) * rstd * g[j] + be[j];
        t = t / (1.f + expf(-t));   // SiLU
        outv[lane * 196 + j] = t;
    }
}

__global__ void k_textbuild(const float* __restrict__ toh, const float* __restrict__ tnm,
                            float* __restrict__ text) {
    int idx = blockIdx.x;           // b*45+c
    int b = idx / 45, c = idx - b * 45;
    int s = threadIdx.x;
    if (s < 196) text[(size_t)idx * 196 + s] = (c < 30) ? toh[b * 196 + s] : tnm[b * 196 + s];
}

// ---------------- GCN ----------------
__global__ void k_gcn_dist(const float* __restrict__ f, float* __restrict__ dist, int C) {
    int idx = blockIdx.x;           // b*C+i
    int b = idx / C;
    __shared__ float fi[196];
    int tid = threadIdx.x;
    for (int n = tid; n < 196; n += blockDim.x) fi[n] = f[(size_t)idx * 196 + n];
    __syncthreads();
    if (tid < C) {
        const float* fj = &f[(size_t)(b * C + tid) * 196];
        float s = 0.f;
        for (int n = 0; n < 196; ++n) s += fabsf(fi[n] - fj[n]);
        dist[(size_t)idx * C + tid] = expf(-s);
    }
}

// fused: tmp = dist @ f ; out = relu(tmp @ wt + b) + f
__global__ void k_gcn_spmmfin(const float* __restrict__ dist, const float* __restrict__ f,
                              const float* __restrict__ wt, const float* __restrict__ bias,
                              float* __restrict__ outp, int C) {
    int idx = blockIdx.x;           // b*C+i
    int b = idx / C;
    __shared__ float ds[128];
    __shared__ float ts[196];
    int tid = threadIdx.x;
    for (int j = tid; j < C; j += 256) ds[j] = dist[(size_t)idx * C + j];
    __syncthreads();
    if (tid < 196) {
        float a = 0.f;
        for (int j = 0; j < C; ++j) a += ds[j] * f[((size_t)b * C + j) * 196 + tid];
        ts[tid] = a;
    }
    __syncthreads();
    if (tid < 196) {
        float a = bias[tid];
        for (int n = 0; n < 196; ++n) a += ts[n] * wt[n * 196 + tid];
        outp[(size_t)idx * 196 + tid] = fmaxf(a, 0.f) + f[(size_t)idx * 196 + tid];
    }
}

// ---------------- fused LayerNorm + relu(linear) ----------------
__global__ void k_lnlin(const float* __restrict__ x, const float* __restrict__ g,
                        const float* __restrict__ be, const float* __restrict__ eT,
                        const float* __restrict__ eb, float* __restrict__ lnout,
                        float* __restrict__ qout) {
    int row = blockIdx.x;
    int tid = threadIdx.x;
    __shared__ float ls[196];
    __shared__ float red[8];
    float v = (tid < 196) ? x[(size_t)row * 196 + tid] : 0.f;
    float s = v, s2 = v * v;
    for (int m = 32; m; m >>= 1) { s += __shfl_xor(s, m); s2 += __shfl_xor(s2, m); }
    if ((tid & 63) == 0) { red[tid >> 6] = s; red[4 + (tid >> 6)] = s2; }
    __syncthreads();
    s = red[0] + red[1] + red[2] + red[3];
    s2 = red[4] + red[5] + red[6] + red[7];
    float mean = s / 196.f;
    float var = s2 / 196.f - mean * mean;
    float rstd = rsqrtf(var + 1e-6f);
    if (tid < 196) {
        float l = (v - mean) * rstd * g[tid] + be[tid];
        ls[tid] = l;
        lnout[(size_t)row * 196 + tid] = l;
    }
    __syncthreads();
    if (tid < 196) {
        float acc = eb[tid];
        for (int n = 0; n < 196; ++n) acc += ls[n] * eT[n * 196 + tid];
        qout[(size_t)row * 196 + tid] = fmaxf(acc, 0.f);
    }
}

// ---------------- fused cross-attention row ----------------
// For row i of "own": scores vs own (RA) and other (RB), two softmaxes,
// two attention-weighted sums, two output projections, + ln residual +
// pre-ln residual -> feat[b, cbase+i, :].
__global__ void k_attrow(const float* __restrict__ own, int RA,
                         const float* __restrict__ oth, int RB,
                         const float* __restrict__ wAT, const float* __restrict__ bA,
                         const float* __restrict__ wBT, const float* __restrict__ bB,
                         const float* __restrict__ lnres, const float* __restrict__ res2,
                         float* __restrict__ feat, int cbase) {
    int i = blockIdx.x, b = blockIdx.y;
    int tid = threadIdx.x;
    __shared__ float qs[196], sA[128], sB[128], fA[196], fB[196];
    __shared__ float red[4];
    const float* ownb = own + (size_t)b * RA * 196;
    const float* othb = oth + (size_t)b * RB * 196;
    for (int n = tid; n < 196; n += 256) qs[n] = ownb[(size_t)i * 196 + n];
    __syncthreads();
    if (tid < RA) {
        const float* kr = ownb + (size_t)tid * 196;
        float a = 0.f;
        for (int n = 0; n < 196; ++n) a += qs[n] * kr[n];
        sA[tid] = a;
    } else if (tid < RA + RB) {
        const float* kr = othb + (size_t)(tid - RA) * 196;
        float a = 0.f;
        for (int n = 0; n < 196; ++n) a += qs[n] * kr[n];
        sB[tid - RA] = a;
    }
    __syncthreads();
    // softmax over sA
    float mA = bmax256((tid < RA) ? sA[tid] : -3.4e38f, red, tid);
    float eA = (tid < RA) ? expf(sA[tid] - mA) : 0.f;
    if (tid < RA) sA[tid] = eA;
    float sumA = bsum256(eA, red, tid);
    // softmax over sB
    float mB = bmax256((tid < RB) ? sB[tid] : -3.4e38f, red, tid);
    float eB = (tid < RB) ? expf(sB[tid] - mB) : 0.f;
    if (tid < RB) sB[tid] = eB;
    float sumB = bsum256(eB, red, tid);
    float invA = 1.f / sumA, invB = 1.f / sumB;
    if (tid < 196) {
        float fa = 0.f, fb = 0.f;
        for (int j = 0; j < RA; ++j) fa += sA[j] * ownb[(size_t)j * 196 + tid];
        for (int j = 0; j < RB; ++j) fb += sB[j] * othb[(size_t)j * 196 + tid];
        fA[tid] = fa * invA;
        fB[tid] = fb * invB;
    }
    __syncthreads();
    if (tid < 196) {
        size_t rrow = ((size_t)b * RA + i) * 196 + tid;
        float acc = bA[tid] + bB[tid] + lnres[rrow] + res2[rrow];
        for (int n = 0; n < 196; ++n)
            acc += fA[n] * wAT[n * 196 + tid] + fB[n] * wBT[n * 196 + tid];
        feat[((size_t)b * 173 + cbase + i) * 196 + tid] = acc;
    }
}

// ---------------- 1x1x1 conv (channel mix), relu, optional residual --------
template <int RES>
__global__ void k_conv1x1(const float* __restrict__ x, const float* __restrict__ w,
                          const float* __restrict__ bias, const float* __restrict__ res,
                          float* __restrict__ out, int C) {
    int o = blockIdx.x, b = blockIdx.y;
    __shared__ float wsm[173];
    for (int c = threadIdx.x; c < C; c += 256) wsm[c] = w[o * C + c];
    __syncthreads();
    int s = threadIdx.x;
    if (s < 196) {
        float acc = bias[o];
        for (int c = 0; c < C; ++c) acc += wsm[c] * x[(size_t)(b * C + c) * 196 + s];
        acc = fmaxf(acc, 0.f);
        if (RES) acc += res[(size_t)(b * C + o) * 196 + s];
        out[(size_t)(b * C + o) * 196 + s] = acc;
    }
}

// ---------------- CMSA attention over positions ----------------
__global__ void k_cmsa_att(const float* __restrict__ q, float* __restrict__ A) {
    int i = blockIdx.x, b = blockIdx.y;   // i in [0,196)
    __shared__ float col[173];
    __shared__ float red[4];
    int tid = threadIdx.x;
    for (int c = tid; c < 173; c += 256) col[c] = q[(size_t)(b * 173 + c) * 196 + i];
    __syncthreads();
    float sc = -3.4e38f;
    if (tid < 196) {
        float acc = 0.f;
        for (int c = 0; c < 173; ++c) acc += col[c] * q[(size_t)(b * 173 + c) * 196 + tid];
        sc = acc;
    }
    float m = bmax256(sc, red, tid);
    float e = (tid < 196) ? expf(sc - m) : 0.f;
    float s = bsum256(e, red, tid);
    if (tid < 196) A[(size_t)(b * 196 + i) * 196 + tid] = e / s;
}

__global__ void k_cmsa_apply(const float* __restrict__ A, const float* __restrict__ q,
                             float* __restrict__ fea) {
    int c = blockIdx.x, b = blockIdx.y;
    __shared__ float qs[196];
    int tid = threadIdx.x;
    for (int n = tid; n < 196; n += 256) qs[n] = q[(size_t)(b * 173 + c) * 196 + n];
    __syncthreads();
    if (tid < 196) {
        float acc = 0.f;
        const float* Ar = &A[(size_t)(b * 196 + tid) * 196];
        for (int j = 0; j < 196; ++j) acc += Ar[j] * qs[j];
        fea[(size_t)(b * 173 + c) * 196 + tid] = acc;
    }
}

// ---------------- final classifier ----------------
__global__ void k_finale(const float* __restrict__ toh, const float* __restrict__ tnm,
                         const float* __restrict__ cms, const float* __restrict__ cls_w,
                         const float* __restrict__ cls_b, float* __restrict__ out) {
    int b = blockIdx.x;
    __shared__ float pcm[173];
    __shared__ float r1[4], r2[4];
    int tid = threadIdx.x;
    float a = (tid < 196) ? toh[b * 196 + tid] : 0.f;
    float c = (tid < 196) ? tnm[b * 196 + tid] : 0.f;
    for (int sh = 32; sh; sh >>= 1) { a += __shfl_xor(a, sh); c += __shfl_xor(c, sh); }
    if ((tid & 63) == 0) { r1[tid >> 6] = a; r2[tid >> 6] = c; }
    if (tid < 173) {
        float s = 0.f;
        const float* p = &cms[(size_t)(b * 173 + tid) * 196];
        for (int n = 0; n < 196; ++n) s += p[n];
        pcm[tid] = s;
    }
    __syncthreads();
    if (tid < 2) {
        float soh = r1[0] + r1[1] + r1[2] + r1[3];
        float snm = r2[0] + r2[1] + r2[2] + r2[3];
        const float* wrow = &cls_w[tid * 218];
        float acc = cls_b[tid];
        float w1 = 0.f, w2 = 0.f;
        for (int k = 0; k < 30; ++k) w1 += wrow[k];
        for (int k = 30; k < 45; ++k) w2 += wrow[k];
        acc += soh * w1 + snm * w2;
        for (int k = 0; k < 173; ++k) acc += wrow[45 + k] * pcm[k];
        out[b * 2 + tid] = acc;
    }
}

// ---------------------------------------------------------------------------
extern "C" void kernel_launch(void* const* d_in, const int* in_sizes, int n_in,
                              void* d_out, int out_size, void* d_ws, size_t ws_size,
                              hipStream_t stream) {
    const float* x      = (const float*)d_in[0];
    const float* oneHot = (const float*)d_in[1];
    const float* num    = (const float*)d_in[2];
    const float* c1_w1  = (const float*)d_in[3];
    const float* c1_g1  = (const float*)d_in[5];
    const float* c1_be1 = (const float*)d_in[6];
    const float* c1_w2  = (const float*)d_in[7];
    const float* c1_g2  = (const float*)d_in[9];
    const float* c1_be2 = (const float*)d_in[10];
    const float* oh_w   = (const float*)d_in[11];
    const float* oh_b   = (const float*)d_in[12];
    const float* oh_g   = (const float*)d_in[13];
    const float* oh_be  = (const float*)d_in[14];
    const float* nm_w   = (const float*)d_in[15];
    const float* nm_b   = (const float*)d_in[16];
    const float* nm_g   = (const float*)d_in[17];
    const float* nm_be  = (const float*)d_in[18];
    const float* gm1_w  = (const float*)d_in[19];
    const float* gm1_b  = (const float*)d_in[20];
    const float* gm2_w  = (const float*)d_in[21];
    const float* gm2_b  = (const float*)d_in[22];
    const float* ln1_g  = (const float*)d_in[23];
    const float* ln1_b  = (const float*)d_in[24];
    const float* ln2_g  = (const float*)d_in[25];
    const float* ln2_b  = (const float*)d_in[26];
    const float* e1_w   = (const float*)d_in[27];
    const float* e1_b   = (const float*)d_in[28];
    const float* e2_w   = (const float*)d_in[29];
    const float* e2_b   = (const float*)d_in[30];
    const float* f1_w   = (const float*)d_in[31];
    const float* f1_b   = (const float*)d_in[32];
    const float* f2_w   = (const float*)d_in[33];
    const float* f2_b   = (const float*)d_in[34];
    const float* f3_w   = (const float*)d_in[35];
    const float* f3_b   = (const float*)d_in[36];
    const float* f4_w   = (const float*)d_in[37];
    const float* f4_b   = (const float*)d_in[38];
    const float* cm_w   = (const float*)d_in[39];
    const float* cm_b   = (const float*)d_in[40];
    const float* cmf_w  = (const float*)d_in[41];
    const float* cmf_b  = (const float*)d_in[42];
    const float* cls_w  = (const float*)d_in[43];
    const float* cls_b  = (const float*)d_in[44];
    float* out = (float*)d_out;
    float* W = (float*)d_ws;

    // ---- workspace layout (floats) ----
    const size_t L = 802816;    // 32*128*196
    const size_t T = 282240;    // 32*45*196
    const size_t F3 = 1085056;  // 32*173*196
    const size_t S2 = 1229312;  // 32*196*196
    const size_t o_A    = 0;          // conv1 -> h (bn-relu in place)
    const size_t o_B    = L;          // conv2 -> conv5 f; later ln1
    const size_t o_C    = 2 * L;      // c5f post-gcn
    const size_t o_iq   = 3 * L;      // iq (also start of conv partials)
    const size_t o_tq   = 4 * L;      // tq
    const size_t o_t1   = 4 * L + T;      // text pre-gcn f
    const size_t o_t3   = 4 * L + 2 * T;  // txf post-gcn
    const size_t o_ln2  = 4 * L + 3 * T;  // ln2
    const size_t o_toh  = 4 * L + 4 * T;
    const size_t o_tnm  = o_toh + 6272;
    const size_t o_st   = o_tnm + 6272;   // bn stats (1024)
    const size_t o_wT   = o_st + 1024;    // 8 transposed 196x196
    const size_t o_feat = o_wT + 8 * 38416;
    const size_t o_q    = o_feat + F3;    // q_cmsa, later cmsa output
    const size_t o_fea  = o_q + F3;       // cmsa fea
    const size_t o_Acm  = o_fea + F3;     // [32,196,196]; also gcn dists earlier
    const size_t o_d1   = o_Acm;          // dist1 (32*128*128)
    const size_t o_d2   = o_Acm + 524288; // dist2 (32*45*45)
    // end = o_Acm + S2 = 9,145,600 floats (~36.6 MB)
    // conv partials occupy [3L, 11L) during convs only; everything there is
    // written after the convs complete.

    float* part = W + o_iq;               // 8*L floats of partials
    float* gm1T = W + o_wT + 0 * 38416;
    float* gm2T = W + o_wT + 1 * 38416;
    float* e1T  = W + o_wT + 2 * 38416;
    float* e2T  = W + o_wT + 3 * 38416;
    float* f1T  = W + o_wT + 4 * 38416;
    float* f2T  = W + o_wT + 5 * 38416;
    float* f3T  = W + o_wT + 6 * 38416;
    float* f4T  = W + o_wT + 7 * 38416;

    // ---- conv1 + reduce + BN + relu -> A ----
    k_conv3d_v3<<<dim3(2, 8, 32), 256, 0, stream>>>(x, c1_w1, part, 320, 40, 128);
    k_reduce_part<<<3136, 256, 0, stream>>>(part, W + o_A, 802816);
    k_bn_stats<<<128, 256, 0, stream>>>(W + o_A, W + o_st, 128);
    k_bn_apply_relu<<<4096, 256, 0, stream>>>(W + o_A, W + o_st, c1_g1, c1_be1, 128);

    // ---- conv2 + reduce + BN + relu -> conv5(f) in B ----
    k_conv3d_v3<<<dim3(2, 8, 32), 256, 0, stream>>>(W + o_A, c1_w2, part, 128, 16, 128);
    k_reduce_part<<<3136, 256, 0, stream>>>(part, W + o_B, 802816);
    k_bn_stats<<<128, 256, 0, stream>>>(W + o_B, W + o_st + 512, 128);
    k_bn_apply_relu<<<4096, 256, 0, stream>>>(W + o_B, W + o_st + 512, c1_g2, c1_be2, 128);

    // ---- weight transposes (AFTER convs: partials overlap o_wT) ----
    P8 p8;
    p8.p[0] = gm1_w; p8.p[1] = gm2_w; p8.p[2] = e1_w; p8.p[3] = e2_w;
    p8.p[4] = f1_w;  p8.p[5] = f2_w;  p8.p[6] = f3_w; p8.p[7] = f4_w;
    k_transpose8<<<dim3(196, 8), 256, 0, stream>>>(p8, W + o_wT);

    // ---- catnum (oneHot / num) -> toh,tnm ; text -> t1 ----
    k_catnum<<<196, 64, 0, stream>>>(oneHot, 24, oh_w, oh_b, oh_g, oh_be, W + o_toh);
    k_catnum<<<196, 64, 0, stream>>>(num, 11, nm_w, nm_b, nm_g, nm_be, W + o_tnm);
    k_textbuild<<<32 * 45, 256, 0, stream>>>(W + o_toh, W + o_tnm, W + o_t1);

    // ---- GCN img: f=B -> c5f in C ----
    k_gcn_dist<<<4096, 128, 0, stream>>>(W + o_B, W + o_d1, 128);
    k_gcn_spmmfin<<<4096, 256, 0, stream>>>(W + o_d1, W + o_B, gm1T, gm1_b, W + o_C, 128);

    // ---- GCN text: f=t1 -> txf in t3 ----
    k_gcn_dist<<<1440, 64, 0, stream>>>(W + o_t1, W + o_d2, 45);
    k_gcn_spmmfin<<<1440, 256, 0, stream>>>(W + o_d2, W + o_t1, gm2T, gm2_b, W + o_t3, 45);

    // ---- LN + q projections ----
    k_lnlin<<<4096, 256, 0, stream>>>(W + o_C, ln1_g, ln1_b, e1T, e1_b, W + o_B, W + o_iq);
    k_lnlin<<<1440, 256, 0, stream>>>(W + o_t3, ln2_g, ln2_b, e2T, e2_b, W + o_ln2, W + o_tq);

    // ---- fused cross-attention + proj + residuals -> feat ----
    k_attrow<<<dim3(128, 32), 256, 0, stream>>>(W + o_iq, 128, W + o_tq, 45,
                                                f1T, f1_b, f3T, f3_b,
                                                W + o_B, W + o_C, W + o_feat, 0);
    k_attrow<<<dim3(45, 32), 256, 0, stream>>>(W + o_tq, 45, W + o_iq, 128,
                                               f2T, f2_b, f4T, f4_b,
                                               W + o_ln2, W + o_t3, W + o_feat, 128);

    // ---- CMSA ----
    k_conv1x1<0><<<dim3(173, 32), 256, 0, stream>>>(W + o_feat, cm_w, cm_b, nullptr,
                                                    W + o_q, 173);
    k_cmsa_att<<<dim3(196, 32), 256, 0, stream>>>(W + o_q, W + o_Acm);
    k_cmsa_apply<<<dim3(173, 32), 256, 0, stream>>>(W + o_Acm, W + o_q, W + o_fea);
    k_conv1x1<1><<<dim3(173, 32), 256, 0, stream>>>(W + o_fea, cmf_w, cmf_b, W + o_feat,
                                                    W + o_q, 173);

    // ---- final classifier ----
    k_finale<<<32, 256, 0, stream>>>(W + o_toh, W + o_tnm, W + o_q, cls_w, cls_b, out);
}

// Round 5
// 781.401 us; speedup vs baseline: 3.0738x; 3.0738x over previous
//
#include <hip/hip_runtime.h>
#include <hip/hip_bf16.h>

// ---------------------------------------------------------------------------
// mv3Dunet_down_text_cmsa forward. Round 5: 3x3x3 convs as 27 shifted
// bf16 MFMA GEMMs (X pre-transposed to [s][ic] bf16 in global, weights
// pre-packed [t][oc][ic] bf16). Tail kept from round 4 (fused attrow etc).
// ---------------------------------------------------------------------------

using bf16x8 = __attribute__((ext_vector_type(8))) short;
using f32x4  = __attribute__((ext_vector_type(4))) float;

__device__ __forceinline__ unsigned short f2bf(float f) {
    unsigned int u = __float_as_uint(f);
    u += 0x7FFFu + ((u >> 16) & 1u);
    return (unsigned short)(u >> 16);
}

__device__ __forceinline__ float bmax256(float v, volatile float* red, int tid) {
    for (int sh = 32; sh; sh >>= 1) v = fmaxf(v, __shfl_xor(v, sh));
    __syncthreads();
    if ((tid & 63) == 0) red[tid >> 6] = v;
    __syncthreads();
    return fmaxf(fmaxf(red[0], red[1]), fmaxf(red[2], red[3]));
}
__device__ __forceinline__ float bsum256(float v, volatile float* red, int tid) {
    for (int sh = 32; sh; sh >>= 1) v += __shfl_xor(v, sh);
    __syncthreads();
    if ((tid & 63) == 0) red[tid >> 6] = v;
    __syncthreads();
    return red[0] + red[1] + red[2] + red[3];
}

// ---------------- X transpose + bf16 cast: x[b][IC][196] -> xt[b][208][ICPAD]
__global__ void k_xt(const float* __restrict__ x, unsigned short* __restrict__ xt,
                     int IC, int ICPAD) {
    int b = blockIdx.y;
    int halfpad = ICPAD >> 1;
    int idx = blockIdx.x * 256 + threadIdx.x;
    if (idx >= 208 * halfpad) return;
    int s = idx / halfpad, icp = idx - s * halfpad;
    int ic = icp * 2;
    unsigned int lo = 0, hi = 0;
    if (s < 196 && ic < IC)     lo = f2bf(x[((size_t)b * IC + ic) * 196 + s]);
    if (s < 196 && ic + 1 < IC) hi = f2bf(x[((size_t)b * IC + ic + 1) * 196 + s]);
    ((unsigned int*)xt)[(size_t)b * 208 * halfpad + idx] = lo | (hi << 16);
}

// ---------------- weight pack: w[oc][ic][27] f32 -> wp[t][oc][ic] bf16 -------
__global__ void k_wpack(const float* __restrict__ w, unsigned short* __restrict__ wp,
                        int IC) {
    int nc = IC >> 3;
    int idx = blockIdx.x * 256 + threadIdx.x;
    if (idx >= 27 * 128 * nc) return;
    int c = idx % nc; int r = idx / nc; int oc = r & 127; int t = r >> 7;
    const float* ws = w + ((size_t)oc * IC + c * 8) * 27 + t;
    unsigned int o0 = f2bf(ws[0])   | ((unsigned int)f2bf(ws[27])  << 16);
    unsigned int o1 = f2bf(ws[54])  | ((unsigned int)f2bf(ws[81])  << 16);
    unsigned int o2 = f2bf(ws[108]) | ((unsigned int)f2bf(ws[135]) << 16);
    unsigned int o3 = f2bf(ws[162]) | ((unsigned int)f2bf(ws[189]) << 16);
    uint4 v; v.x = o0; v.y = o1; v.z = o2; v.w = o3;
    ((uint4*)wp)[idx] = v;
}

// ---------------- MFMA conv: 27 shifted GEMMs -------------------------------
// A = XT rows (s-shifted per tap), B = Wpack[t][oc][ic]. 4 waves split M
// (13 tiles of 16, overlapped), each wave does all 8 N-tiles. Partials per
// K-group g (6 groups of NU (tap,kk)-units) -> part[g][b][oc][s].
template <int IC, int ICPAD, int NU, int KKPT>
__global__ __launch_bounds__(256, 1) void k_convmfma(
    const unsigned short* __restrict__ xt, const unsigned short* __restrict__ wp,
    float* __restrict__ part) {
    extern __shared__ char smem_c[];
    const int tid = threadIdx.x;
    const int g = blockIdx.x, b = blockIdx.y;

    // stage XT[b] into LDS (layout identical, linear copy)
    {
        const bf16x8* s8 = (const bf16x8*)(xt + (size_t)b * 208 * ICPAD);
        bf16x8* d8 = (bf16x8*)smem_c;
        for (int c = tid; c < 208 * ICPAD / 8; c += 256) d8[c] = s8[c];
    }
    __syncthreads();

    const int lane = tid & 63;
    const int wv = tid >> 6;
    const int a = lane & 15, kg = lane >> 4;

    int md[4], mh[4], mw[4];
#pragma unroll
    for (int i = 0; i < 4; ++i) {
        int m = (3 * wv + i) * 16 + a;
        md[i] = m / 49; int rr = m - md[i] * 49;
        mh[i] = rr / 7; mw[i] = rr - mh[i] * 7;
    }

    f32x4 acc[4][8];
#pragma unroll
    for (int i = 0; i < 4; ++i)
#pragma unroll
        for (int nt = 0; nt < 8; ++nt) acc[i][nt] = (f32x4){0.f, 0.f, 0.f, 0.f};

    const bf16x8 zv = {0, 0, 0, 0, 0, 0, 0, 0};
    int rsrc[4]; bool ok[4];
    int tcur = -1;
    for (int u = g * NU; u < (g + 1) * NU; ++u) {
        int t = u / KKPT, kk = u - t * KKPT;
        if (t != tcur) {
            tcur = t;
            int kd = t / 9, kh = (t / 3) % 3, kw = t % 3;
#pragma unroll
            for (int i = 0; i < 4; ++i) {
                int d2 = md[i] + kd - 1, h2 = mh[i] + kh - 1, w2 = mw[i] + kw - 1;
                ok[i] = ((unsigned)d2 < 4u) & ((unsigned)h2 < 7u) & ((unsigned)w2 < 7u);
                rsrc[i] = ok[i] ? (d2 * 49 + h2 * 7 + w2) : 0;
            }
        }
        int kb = kk * 32 + kg * 8;   // element offset within row
        bf16x8 A[4];
#pragma unroll
        for (int i = 0; i < 4; ++i) {
            bf16x8 v = *(const bf16x8*)(smem_c + ((size_t)rsrc[i] * ICPAD + kb) * 2);
            A[i] = ok[i] ? v : zv;
        }
        const unsigned short* wrow = wp + ((size_t)t * 128 + a) * IC + kb;
#pragma unroll
        for (int nt = 0; nt < 8; ++nt) {
            bf16x8 B = *(const bf16x8*)(wrow + (size_t)nt * 16 * IC);
#pragma unroll
            for (int i = 0; i < 4; ++i)
                acc[i][nt] = __builtin_amdgcn_mfma_f32_16x16x32_bf16(A[i], B, acc[i][nt], 0, 0, 0);
        }
    }

    float* dst = part + ((size_t)g * 32 + b) * (128 * 196);
#pragma unroll
    for (int i = 0; i < 4; ++i) {
        int m0 = (3 * wv + i) * 16 + kg * 4;
        if (m0 < 196) {
#pragma unroll
            for (int nt = 0; nt < 8; ++nt) {
                int oc = nt * 16 + a;
                *(f32x4*)(dst + (size_t)oc * 196 + m0) = acc[i][nt];
            }
        }
    }
}

// sum 6 partials
__global__ void k_reduce6(const float* __restrict__ part, float* __restrict__ y, int n) {
    int i = blockIdx.x * blockDim.x + threadIdx.x;
    if (i < n) {
        float s = 0.f;
#pragma unroll
        for (int g = 0; g < 6; ++g) s += part[(size_t)g * n + i];
        y[i] = s;
    }
}

// ---------------- fused transpose of 8 [196,196] matrices ----------------
struct P8 { const float* p[8]; };
__global__ void k_transpose8(P8 ws_in, float* __restrict__ wt) {
    int i = blockIdx.x, m = blockIdx.y;
    const float* w = ws_in.p[m];
    float* o = wt + (size_t)m * 38416;
    for (int t = threadIdx.x; t < 196; t += blockDim.x)
        o[(size_t)i * 196 + t] = w[(size_t)t * 196 + i];
}

// ---------------- BN (training mode, axes 0,2,3,4) ----------------
__global__ void k_bn_stats(const float* __restrict__ y, float* __restrict__ stats,
                           int C) {
    int ch = blockIdx.x; int tid = threadIdx.x;
    float s = 0.f, s2 = 0.f;
    for (int b = 0; b < 32; ++b) {
        const float* p = &y[(size_t)(b * C + ch) * 196];
        for (int i = tid; i < 196; i += 256) { float v = p[i]; s += v; s2 += v * v; }
    }
    __shared__ float r1[4], r2[4];
    for (int sh = 32; sh; sh >>= 1) { s += __shfl_xor(s, sh); s2 += __shfl_xor(s2, sh); }
    if ((tid & 63) == 0) { r1[tid >> 6] = s; r2[tid >> 6] = s2; }
    __syncthreads();
    if (tid == 0) {
        float S = r1[0] + r1[1] + r1[2] + r1[3];
        float S2 = r2[0] + r2[1] + r2[2] + r2[3];
        float m = S / 6272.f;
        float v = S2 / 6272.f - m * m;
        stats[2 * ch] = m;
        stats[2 * ch + 1] = rsqrtf(v + 1e-5f);
    }
}

__global__ void k_bn_apply_relu(float* __restrict__ y, const float* __restrict__ stats,
                                const float* __restrict__ g, const float* __restrict__ be,
                                int C) {
    int idx = blockIdx.x;           // b*C + ch
    int ch = idx % C;
    int s = threadIdx.x;
    if (s < 196) {
        float m = stats[2 * ch], r = stats[2 * ch + 1];
        float v = y[(size_t)idx * 196 + s];
        y[(size_t)idx * 196 + s] = fmaxf((v - m) * r * g[ch] + be[ch], 0.f);
    }
}

// ---------------- catnum: Linear(A->196) + BN over batch + SiLU -------------
__global__ void k_catnum(const float* __restrict__ inp, int A,
                         const float* __restrict__ w, const float* __restrict__ bias,
                         const float* __restrict__ g, const float* __restrict__ be,
                         float* __restrict__ outv) {
    int j = blockIdx.x;             // feature 0..195
    int lane = threadIdx.x;         // 64 threads, 32 active
    float v = 0.f;
    if (lane < 32) {
        v = bias[j];
        for (int k = 0; k < A; ++k) v += inp[lane * A + k] * w[j * A + k];
    }
    float s = (lane < 32) ? v : 0.f;
    float s2 = (lane < 32) ? v * v : 0.f;
    for (int m = 16; m; m >>= 1) { s += __shfl_xor(s, m, 32); s2 += __shfl_xor(s2, m, 32); }
    if (lane < 32) {
        float mean = s / 32.f;
        float var = s2 / 32.f - mean * mean;
        float rstd = rsqrtf(var + 1e-5f);
        float t = (v - mean) * rstd * g[j] + be[j];
        t = t / (1.f + expf(-t));   // SiLU
        outv[lane * 196 + j] = t;
    }
}

__global__ void k_textbuild(const float* __restrict__ toh, const float* __restrict__ tnm,
                            float* __restrict__ text) {
    int idx = blockIdx.x;           // b*45+c
    int b = idx / 45, c = idx - b * 45;
    int s = threadIdx.x;
    if (s < 196) text[(size_t)idx * 196 + s] = (c < 30) ? toh[b * 196 + s] : tnm[b * 196 + s];
}

// ---------------- GCN ----------------
__global__ void k_gcn_dist(const float* __restrict__ f, float* __restrict__ dist, int C) {
    int idx = blockIdx.x;           // b*C+i
    int b = idx / C;
    __shared__ float fi[196];
    int tid = threadIdx.x;
    for (int n = tid; n < 196; n += blockDim.x) fi[n] = f[(size_t)idx * 196 + n];
    __syncthreads();
    if (tid < C) {
        const float* fj = &f[(size_t)(b * C + tid) * 196];
        float s = 0.f;
        for (int n = 0; n < 196; ++n) s += fabsf(fi[n] - fj[n]);
        dist[(size_t)idx * C + tid] = expf(-s);
    }
}

// fused: tmp = dist @ f ; out = relu(tmp @ wt + b) + f
__global__ void k_gcn_spmmfin(const float* __restrict__ dist, const float* __restrict__ f,
                              const float* __restrict__ wt, const float* __restrict__ bias,
                              float* __restrict__ outp, int C) {
    int idx = blockIdx.x;           // b*C+i
    int b = idx / C;
    __shared__ float ds[128];
    __shared__ float ts[196];
    int tid = threadIdx.x;
    for (int j = tid; j < C; j += 256) ds[j] = dist[(size_t)idx * C + j];
    __syncthreads();
    if (tid < 196) {
        float a = 0.f;
        for (int j = 0; j < C; ++j) a += ds[j] * f[((size_t)b * C + j) * 196 + tid];
        ts[tid] = a;
    }
    __syncthreads();
    if (tid < 196) {
        float a = bias[tid];
        for (int n = 0; n < 196; ++n) a += ts[n] * wt[n * 196 + tid];
        outp[(size_t)idx * 196 + tid] = fmaxf(a, 0.f) + f[(size_t)idx * 196 + tid];
    }
}

// ---------------- fused LayerNorm + relu(linear) ----------------
__global__ void k_lnlin(const float* __restrict__ x, const float* __restrict__ g,
                        const float* __restrict__ be, const float* __restrict__ eT,
                        const float* __restrict__ eb, float* __restrict__ lnout,
                        float* __restrict__ qout) {
    int row = blockIdx.x;
    int tid = threadIdx.x;
    __shared__ float ls[196];
    __shared__ float red[8];
    float v = (tid < 196) ? x[(size_t)row * 196 + tid] : 0.f;
    float s = v, s2 = v * v;
    for (int m = 32; m; m >>= 1) { s += __shfl_xor(s, m); s2 += __shfl_xor(s2, m); }
    if ((tid & 63) == 0) { red[tid >> 6] = s; red[4 + (tid >> 6)] = s2; }
    __syncthreads();
    s = red[0] + red[1] + red[2] + red[3];
    s2 = red[4] + red[5] + red[6] + red[7];
    float mean = s / 196.f;
    float var = s2 / 196.f - mean * mean;
    float rstd = rsqrtf(var + 1e-6f);
    if (tid < 196) {
        float l = (v - mean) * rstd * g[tid] + be[tid];
        ls[tid] = l;
        lnout[(size_t)row * 196 + tid] = l;
    }
    __syncthreads();
    if (tid < 196) {
        float acc = eb[tid];
        for (int n = 0; n < 196; ++n) acc += ls[n] * eT[n * 196 + tid];
        qout[(size_t)row * 196 + tid] = fmaxf(acc, 0.f);
    }
}

// ---------------- fused cross-attention row ----------------
__global__ void k_attrow(const float* __restrict__ own, int RA,
                         const float* __restrict__ oth, int RB,
                         const float* __restrict__ wAT, const float* __restrict__ bA,
                         const float* __restrict__ wBT, const float* __restrict__ bB,
                         const float* __restrict__ lnres, const float* __restrict__ res2,
                         float* __restrict__ feat, int cbase) {
    int i = blockIdx.x, b = blockIdx.y;
    int tid = threadIdx.x;
    __shared__ float qs[196], sA[128], sB[128], fA[196], fB[196];
    __shared__ float red[4];
    const float* ownb = own + (size_t)b * RA * 196;
    const float* othb = oth + (size_t)b * RB * 196;
    for (int n = tid; n < 196; n += 256) qs[n] = ownb[(size_t)i * 196 + n];
    __syncthreads();
    if (tid < RA) {
        const float* kr = ownb + (size_t)tid * 196;
        float a = 0.f;
        for (int n = 0; n < 196; ++n) a += qs[n] * kr[n];
        sA[tid] = a;
    } else if (tid < RA + RB) {
        const float* kr = othb + (size_t)(tid - RA) * 196;
        float a = 0.f;
        for (int n = 0; n < 196; ++n) a += qs[n] * kr[n];
        sB[tid - RA] = a;
    }
    __syncthreads();
    float mA = bmax256((tid < RA) ? sA[tid] : -3.4e38f, red, tid);
    float eA = (tid < RA) ? expf(sA[tid] - mA) : 0.f;
    if (tid < RA) sA[tid] = eA;
    float sumA = bsum256(eA, red, tid);
    float mB = bmax256((tid < RB) ? sB[tid] : -3.4e38f, red, tid);
    float eB = (tid < RB) ? expf(sB[tid] - mB) : 0.f;
    if (tid < RB) sB[tid] = eB;
    float sumB = bsum256(eB, red, tid);
    float invA = 1.f / sumA, invB = 1.f / sumB;
    if (tid < 196) {
        float fa = 0.f, fb = 0.f;
        for (int j = 0; j < RA; ++j) fa += sA[j] * ownb[(size_t)j * 196 + tid];
        for (int j = 0; j < RB; ++j) fb += sB[j] * othb[(size_t)j * 196 + tid];
        fA[tid] = fa * invA;
        fB[tid] = fb * invB;
    }
    __syncthreads();
    if (tid < 196) {
        size_t rrow = ((size_t)b * RA + i) * 196 + tid;
        float acc = bA[tid] + bB[tid] + lnres[rrow] + res2[rrow];
        for (int n = 0; n < 196; ++n)
            acc += fA[n] * wAT[n * 196 + tid] + fB[n] * wBT[n * 196 + tid];
        feat[((size_t)b * 173 + cbase + i) * 196 + tid] = acc;
    }
}

// ---------------- 1x1x1 conv (channel mix), relu, optional residual --------
template <int RES>
__global__ void k_conv1x1(const float* __restrict__ x, const float* __restrict__ w,
                          const float* __restrict__ bias, const float* __restrict__ res,
                          float* __restrict__ out, int C) {
    int o = blockIdx.x, b = blockIdx.y;
    __shared__ float wsm[173];
    for (int c = threadIdx.x; c < C; c += 256) wsm[c] = w[o * C + c];
    __syncthreads();
    int s = threadIdx.x;
    if (s < 196) {
        float acc = bias[o];
        for (int c = 0; c < C; ++c) acc += wsm[c] * x[(size_t)(b * C + c) * 196 + s];
        acc = fmaxf(acc, 0.f);
        if (RES) acc += res[(size_t)(b * C + o) * 196 + s];
        out[(size_t)(b * C + o) * 196 + s] = acc;
    }
}

// ---------------- CMSA attention over positions ----------------
__global__ void k_cmsa_att(const float* __restrict__ q, float* __restrict__ A) {
    int i = blockIdx.x, b = blockIdx.y;   // i in [0,196)
    __shared__ float col[173];
    __shared__ float red[4];
    int tid = threadIdx.x;
    for (int c = tid; c < 173; c += 256) col[c] = q[(size_t)(b * 173 + c) * 196 + i];
    __syncthreads();
    float sc = -3.4e38f;
    if (tid < 196) {
        float acc = 0.f;
        for (int c = 0; c < 173; ++c) acc += col[c] * q[(size_t)(b * 173 + c) * 196 + tid];
        sc = acc;
    }
    float m = bmax256(sc, red, tid);
    float e = (tid < 196) ? expf(sc - m) : 0.f;
    float s = bsum256(e, red, tid);
    if (tid < 196) A[(size_t)(b * 196 + i) * 196 + tid] = e / s;
}

__global__ void k_cmsa_apply(const float* __restrict__ A, const float* __restrict__ q,
                             float* __restrict__ fea) {
    int c = blockIdx.x, b = blockIdx.y;
    __shared__ float qs[196];
    int tid = threadIdx.x;
    for (int n = tid; n < 196; n += 256) qs[n] = q[(size_t)(b * 173 + c) * 196 + n];
    __syncthreads();
    if (tid < 196) {
        float acc = 0.f;
        const float* Ar = &A[(size_t)(b * 196 + tid) * 196];
        for (int j = 0; j < 196; ++j) acc += Ar[j] * qs[j];
        fea[(size_t)(b * 173 + c) * 196 + tid] = acc;
    }
}

// ---------------- final classifier ----------------
__global__ void k_finale(const float* __restrict__ toh, const float* __restrict__ tnm,
                         const float* __restrict__ cms, const float* __restrict__ cls_w,
                         const float* __restrict__ cls_b, float* __restrict__ out) {
    int b = blockIdx.x;
    __shared__ float pcm[173];
    __shared__ float r1[4], r2[4];
    int tid = threadIdx.x;
    float a = (tid < 196) ? toh[b * 196 + tid] : 0.f;
    float c = (tid < 196) ? tnm[b * 196 + tid] : 0.f;
    for (int sh = 32; sh; sh >>= 1) { a += __shfl_xor(a, sh); c += __shfl_xor(c, sh); }
    if ((tid & 63) == 0) { r1[tid >> 6] = a; r2[tid >> 6] = c; }
    if (tid < 173) {
        float s = 0.f;
        const float* p = &cms[(size_t)(b * 173 + tid) * 196];
        for (int n = 0; n < 196; ++n) s += p[n];
        pcm[tid] = s;
    }
    __syncthreads();
    if (tid < 2) {
        float soh = r1[0] + r1[1] + r1[2] + r1[3];
        float snm = r2[0] + r2[1] + r2[2] + r2[3];
        const float* wrow = &cls_w[tid * 218];
        float acc = cls_b[tid];
        float w1 = 0.f, w2 = 0.f;
        for (int k = 0; k < 30; ++k) w1 += wrow[k];
        for (int k = 30; k < 45; ++k) w2 += wrow[k];
        acc += soh * w1 + snm * w2;
        for (int k = 0; k < 173; ++k) acc += wrow[45 + k] * pcm[k];
        out[b * 2 + tid] = acc;
    }
}

// ---------------------------------------------------------------------------
extern "C" void kernel_launch(void* const* d_in, const int* in_sizes, int n_in,
                              void* d_out, int out_size, void* d_ws, size_t ws_size,
                              hipStream_t stream) {
    const float* x      = (const float*)d_in[0];
    const float* oneHot = (const float*)d_in[1];
    const float* num    = (const float*)d_in[2];
    const float* c1_w1  = (const float*)d_in[3];
    const float* c1_g1  = (const float*)d_in[5];
    const float* c1_be1 = (const float*)d_in[6];
    const float* c1_w2  = (const float*)d_in[7];
    const float* c1_g2  = (const float*)d_in[9];
    const float* c1_be2 = (const float*)d_in[10];
    const float* oh_w   = (const float*)d_in[11];
    const float* oh_b   = (const float*)d_in[12];
    const float* oh_g   = (const float*)d_in[13];
    const float* oh_be  = (const float*)d_in[14];
    const float* nm_w   = (const float*)d_in[15];
    const float* nm_b   = (const float*)d_in[16];
    const float* nm_g   = (const float*)d_in[17];
    const float* nm_be  = (const float*)d_in[18];
    const float* gm1_w  = (const float*)d_in[19];
    const float* gm1_b  = (const float*)d_in[20];
    const float* gm2_w  = (const float*)d_in[21];
    const float* gm2_b  = (const float*)d_in[22];
    const float* ln1_g  = (const float*)d_in[23];
    const float* ln1_b  = (const float*)d_in[24];
    const float* ln2_g  = (const float*)d_in[25];
    const float* ln2_b  = (const float*)d_in[26];
    const float* e1_w   = (const float*)d_in[27];
    const float* e1_b   = (const float*)d_in[28];
    const float* e2_w   = (const float*)d_in[29];
    const float* e2_b   = (const float*)d_in[30];
    const float* f1_w   = (const float*)d_in[31];
    const float* f1_b   = (const float*)d_in[32];
    const float* f2_w   = (const float*)d_in[33];
    const float* f2_b   = (const float*)d_in[34];
    const float* f3_w   = (const float*)d_in[35];
    const float* f3_b   = (const float*)d_in[36];
    const float* f4_w   = (const float*)d_in[37];
    const float* f4_b   = (const float*)d_in[38];
    const float* cm_w   = (const float*)d_in[39];
    const float* cm_b   = (const float*)d_in[40];
    const float* cmf_w  = (const float*)d_in[41];
    const float* cmf_b  = (const float*)d_in[42];
    const float* cls_w  = (const float*)d_in[43];
    const float* cls_b  = (const float*)d_in[44];
    float* out = (float*)d_out;
    float* W = (float*)d_ws;

    // ---- workspace layout (floats) ----
    const size_t L = 802816;    // 32*128*196
    const size_t T = 282240;    // 32*45*196
    const size_t F3 = 1085056;  // 32*173*196
    const size_t S2 = 1229312;  // 32*196*196
    const size_t o_A    = 0;          // conv1 -> h (bn-relu in place)
    const size_t o_B    = L;          // conv2 -> conv5 f; later ln1
    const size_t o_C    = 2 * L;      // c5f post-gcn
    const size_t o_part = 3 * L;      // conv partials, 6 groups -> [3L, 9L)
    const size_t o_iq   = 3 * L;      // iq (post-conv)
    const size_t o_tq   = 4 * L;      // tq
    const size_t o_t1   = 4 * L + T;      // text pre-gcn f
    const size_t o_t3   = 4 * L + 2 * T;  // txf post-gcn
    const size_t o_ln2  = 4 * L + 3 * T;  // ln2
    const size_t o_toh  = 4 * L + 4 * T;
    const size_t o_tnm  = o_toh + 6272;
    const size_t o_st   = o_tnm + 6272;   // bn stats (1024)
    const size_t o_wT   = o_st + 1024;    // 8 transposed 196x196
    const size_t o_feat = o_wT + 8 * 38416;
    const size_t o_q    = o_feat + F3;    // q_cmsa, later cmsa output
    const size_t o_fea  = o_q + F3;       // cmsa fea
    const size_t o_Acm  = o_fea + F3;     // [32,196,196]; also gcn dists
    const size_t o_d1   = o_Acm;          // dist1 (32*128*128)
    const size_t o_d2   = o_Acm + 524288; // dist2 (32*45*45)
    // conv-phase-only buffers (dead once convs complete), overlapping the
    // post-conv region o_Acm and extending past it:
    const size_t o_xt1 = 9 * L;                 // 1,091,584 floats (bf16 32x208x328)
    const size_t o_xt2 = o_xt1 + 1091584;       //   452,608 floats (bf16 32x208x136)
    const size_t o_wp1 = o_xt2 + 452608;        //   552,960 floats (bf16 27x128x320)
    const size_t o_wp2 = o_wp1 + 552960;        //   221,184 floats (bf16 27x128x128)
    // end = 9,543,680 floats = 38.2 MB

    float* part = W + o_part;
    unsigned short* xt1 = (unsigned short*)(W + o_xt1);
    unsigned short* xt2 = (unsigned short*)(W + o_xt2);
    unsigned short* wp1 = (unsigned short*)(W + o_wp1);
    unsigned short* wp2 = (unsigned short*)(W + o_wp2);
    float* gm1T = W + o_wT + 0 * 38416;
    float* gm2T = W + o_wT + 1 * 38416;
    float* e1T  = W + o_wT + 2 * 38416;
    float* e2T  = W + o_wT + 3 * 38416;
    float* f1T  = W + o_wT + 4 * 38416;
    float* f2T  = W + o_wT + 5 * 38416;
    float* f3T  = W + o_wT + 6 * 38416;
    float* f4T  = W + o_wT + 7 * 38416;

    // allow >64KB dynamic LDS for the conv kernel
    hipFuncSetAttribute((const void*)&k_convmfma<320, 328, 45, 10>,
                        hipFuncAttributeMaxDynamicSharedMemorySize, 208 * 328 * 2);
    hipFuncSetAttribute((const void*)&k_convmfma<128, 136, 18, 4>,
                        hipFuncAttributeMaxDynamicSharedMemorySize, 208 * 136 * 2);

    // ---- conv prep: pack weights, transpose x ----
    k_wpack<<<(27 * 128 * 40 + 255) / 256, 256, 0, stream>>>(c1_w1, wp1, 320);
    k_wpack<<<(27 * 128 * 16 + 255) / 256, 256, 0, stream>>>(c1_w2, wp2, 128);
    k_xt<<<dim3((208 * 164 + 255) / 256, 32), 256, 0, stream>>>(x, xt1, 320, 328);

    // ---- conv1 (MFMA) + reduce + BN + relu -> A ----
    k_convmfma<320, 328, 45, 10><<<dim3(6, 32), 256, 208 * 328 * 2, stream>>>(xt1, wp1, part);
    k_reduce6<<<3136, 256, 0, stream>>>(part, W + o_A, 802816);
    k_bn_stats<<<128, 256, 0, stream>>>(W + o_A, W + o_st, 128);
    k_bn_apply_relu<<<4096, 256, 0, stream>>>(W + o_A, W + o_st, c1_g1, c1_be1, 128);

    // ---- conv2 (MFMA) + reduce + BN + relu -> conv5(f) in B ----
    k_xt<<<dim3((208 * 68 + 255) / 256, 32), 256, 0, stream>>>(W + o_A, xt2, 128, 136);
    k_convmfma<128, 136, 18, 4><<<dim3(6, 32), 256, 208 * 136 * 2, stream>>>(xt2, wp2, part);
    k_reduce6<<<3136, 256, 0, stream>>>(part, W + o_B, 802816);
    k_bn_stats<<<128, 256, 0, stream>>>(W + o_B, W + o_st + 512, 128);
    k_bn_apply_relu<<<4096, 256, 0, stream>>>(W + o_B, W + o_st + 512, c1_g2, c1_be2, 128);

    // ---- weight transposes (post-conv region) ----
    P8 p8;
    p8.p[0] = gm1_w; p8.p[1] = gm2_w; p8.p[2] = e1_w; p8.p[3] = e2_w;
    p8.p[4] = f1_w;  p8.p[5] = f2_w;  p8.p[6] = f3_w; p8.p[7] = f4_w;
    k_transpose8<<<dim3(196, 8), 256, 0, stream>>>(p8, W + o_wT);

    // ---- catnum (oneHot / num) -> toh,tnm ; text -> t1 ----
    k_catnum<<<196, 64, 0, stream>>>(oneHot, 24, oh_w, oh_b, oh_g, oh_be, W + o_toh);
    k_catnum<<<196, 64, 0, stream>>>(num, 11, nm_w, nm_b, nm_g, nm_be, W + o_tnm);
    k_textbuild<<<32 * 45, 256, 0, stream>>>(W + o_toh, W + o_tnm, W + o_t1);

    // ---- GCN img: f=B -> c5f in C ----
    k_gcn_dist<<<4096, 128, 0, stream>>>(W + o_B, W + o_d1, 128);
    k_gcn_spmmfin<<<4096, 256, 0, stream>>>(W + o_d1, W + o_B, gm1T, gm1_b, W + o_C, 128);

    // ---- GCN text: f=t1 -> txf in t3 ----
    k_gcn_dist<<<1440, 64, 0, stream>>>(W + o_t1, W + o_d2, 45);
    k_gcn_spmmfin<<<1440, 256, 0, stream>>>(W + o_d2, W + o_t1, gm2T, gm2_b, W + o_t3, 45);

    // ---- LN + q projections ----
    k_lnlin<<<4096, 256, 0, stream>>>(W + o_C, ln1_g, ln1_b, e1T, e1_b, W + o_B, W + o_iq);
    k_lnlin<<<1440, 256, 0, stream>>>(W + o_t3, ln2_g, ln2_b, e2T, e2_b, W + o_ln2, W + o_tq);

    // ---- fused cross-attention + proj + residuals -> feat ----
    k_attrow<<<dim3(128, 32), 256, 0, stream>>>(W + o_iq, 128, W + o_tq, 45,
                                                f1T, f1_b, f3T, f3_b,
                                                W + o_B, W + o_C, W + o_feat, 0);
    k_attrow<<<dim3(45, 32), 256, 0, stream>>>(W + o_tq, 45, W + o_iq, 128,
                                               f2T, f2_b, f4T, f4_b,
                                               W + o_ln2, W + o_t3, W + o_feat, 128);

    // ---- CMSA ----
    k_conv1x1<0><<<dim3(173, 32), 256, 0, stream>>>(W + o_feat, cm_w, cm_b, nullptr,
                                                    W + o_q, 173);
    k_cmsa_att<<<dim3(196, 32), 256, 0, stream>>>(W + o_q, W + o_Acm);
    k_cmsa_apply<<<dim3(173, 32), 256, 0, stream>>>(W + o_Acm, W + o_q, W + o_fea);
    k_conv1x1<1><<<dim3(173, 32), 256, 0, stream>>>(W + o_fea, cmf_w, cmf_b, W + o_feat,
                                                    W + o_q, 173);

    // ---- final classifier ----
    k_finale<<<32, 256, 0, stream>>>(W + o_toh, W + o_tnm, W + o_q, cls_w, cls_b, out);
}

// Round 6
// 689.470 us; speedup vs baseline: 3.4836x; 1.1333x over previous
//
#include <hip/hip_runtime.h>
#include <hip/hip_bf16.h>

// ---------------------------------------------------------------------------
// mv3Dunet_down_text_cmsa forward. Round 6: MFMA convs (round 5) + fully
// coalesced tail: transposed twins for every per-lane-row read pattern,
// template loop bounds for unroll/ILP, rowsum fused into last conv1x1.
// ---------------------------------------------------------------------------

using bf16x8 = __attribute__((ext_vector_type(8))) short;
using f32x4  = __attribute__((ext_vector_type(4))) float;

__device__ __forceinline__ unsigned short f2bf(float f) {
    unsigned int u = __float_as_uint(f);
    u += 0x7FFFu + ((u >> 16) & 1u);
    return (unsigned short)(u >> 16);
}

__device__ __forceinline__ float bmax256(float v, volatile float* red, int tid) {
    for (int sh = 32; sh; sh >>= 1) v = fmaxf(v, __shfl_xor(v, sh));
    __syncthreads();
    if ((tid & 63) == 0) red[tid >> 6] = v;
    __syncthreads();
    return fmaxf(fmaxf(red[0], red[1]), fmaxf(red[2], red[3]));
}
__device__ __forceinline__ float bsum256(float v, volatile float* red, int tid) {
    for (int sh = 32; sh; sh >>= 1) v += __shfl_xor(v, sh);
    __syncthreads();
    if ((tid & 63) == 0) red[tid >> 6] = v;
    __syncthreads();
    return red[0] + red[1] + red[2] + red[3];
}

// ---------------- X transpose + bf16 cast: x[b][IC][196] -> xt[b][208][ICPAD]
__global__ void k_xt(const float* __restrict__ x, unsigned short* __restrict__ xt,
                     int IC, int ICPAD) {
    int b = blockIdx.y;
    int halfpad = ICPAD >> 1;
    int idx = blockIdx.x * 256 + threadIdx.x;
    if (idx >= 208 * halfpad) return;
    int s = idx / halfpad, icp = idx - s * halfpad;
    int ic = icp * 2;
    unsigned int lo = 0, hi = 0;
    if (s < 196 && ic < IC)     lo = f2bf(x[((size_t)b * IC + ic) * 196 + s]);
    if (s < 196 && ic + 1 < IC) hi = f2bf(x[((size_t)b * IC + ic + 1) * 196 + s]);
    ((unsigned int*)xt)[(size_t)b * 208 * halfpad + idx] = lo | (hi << 16);
}

// ---------------- weight pack: w[oc][ic][27] f32 -> wp[t][oc][ic] bf16 -------
__global__ void k_wpack(const float* __restrict__ w, unsigned short* __restrict__ wp,
                        int IC) {
    int nc = IC >> 3;
    int idx = blockIdx.x * 256 + threadIdx.x;
    if (idx >= 27 * 128 * nc) return;
    int c = idx % nc; int r = idx / nc; int oc = r & 127; int t = r >> 7;
    const float* ws = w + ((size_t)oc * IC + c * 8) * 27 + t;
    unsigned int o0 = f2bf(ws[0])   | ((unsigned int)f2bf(ws[27])  << 16);
    unsigned int o1 = f2bf(ws[54])  | ((unsigned int)f2bf(ws[81])  << 16);
    unsigned int o2 = f2bf(ws[108]) | ((unsigned int)f2bf(ws[135]) << 16);
    unsigned int o3 = f2bf(ws[162]) | ((unsigned int)f2bf(ws[189]) << 16);
    uint4 v; v.x = o0; v.y = o1; v.z = o2; v.w = o3;
    ((uint4*)wp)[idx] = v;
}

// ---------------- MFMA conv: 27 shifted GEMMs -------------------------------
template <int IC, int ICPAD, int NU, int KKPT>
__global__ __launch_bounds__(256, 1) void k_convmfma(
    const unsigned short* __restrict__ xt, const unsigned short* __restrict__ wp,
    float* __restrict__ part) {
    extern __shared__ char smem_c[];
    const int tid = threadIdx.x;
    const int g = blockIdx.x, b = blockIdx.y;

    {
        const bf16x8* s8 = (const bf16x8*)(xt + (size_t)b * 208 * ICPAD);
        bf16x8* d8 = (bf16x8*)smem_c;
        for (int c = tid; c < 208 * ICPAD / 8; c += 256) d8[c] = s8[c];
    }
    __syncthreads();

    const int lane = tid & 63;
    const int wv = tid >> 6;
    const int a = lane & 15, kg = lane >> 4;

    int md[4], mh[4], mw[4];
#pragma unroll
    for (int i = 0; i < 4; ++i) {
        int m = (3 * wv + i) * 16 + a;
        md[i] = m / 49; int rr = m - md[i] * 49;
        mh[i] = rr / 7; mw[i] = rr - mh[i] * 7;
    }

    f32x4 acc[4][8];
#pragma unroll
    for (int i = 0; i < 4; ++i)
#pragma unroll
        for (int nt = 0; nt < 8; ++nt) acc[i][nt] = (f32x4){0.f, 0.f, 0.f, 0.f};

    const bf16x8 zv = {0, 0, 0, 0, 0, 0, 0, 0};
    int rsrc[4]; bool ok[4];
    int tcur = -1;
    for (int u = g * NU; u < (g + 1) * NU; ++u) {
        int t = u / KKPT, kk = u - t * KKPT;
        if (t != tcur) {
            tcur = t;
            int kd = t / 9, kh = (t / 3) % 3, kw = t % 3;
#pragma unroll
            for (int i = 0; i < 4; ++i) {
                int d2 = md[i] + kd - 1, h2 = mh[i] + kh - 1, w2 = mw[i] + kw - 1;
                ok[i] = ((unsigned)d2 < 4u) & ((unsigned)h2 < 7u) & ((unsigned)w2 < 7u);
                rsrc[i] = ok[i] ? (d2 * 49 + h2 * 7 + w2) : 0;
            }
        }
        int kb = kk * 32 + kg * 8;
        bf16x8 A[4];
#pragma unroll
        for (int i = 0; i < 4; ++i) {
            bf16x8 v = *(const bf16x8*)(smem_c + ((size_t)rsrc[i] * ICPAD + kb) * 2);
            A[i] = ok[i] ? v : zv;
        }
        const unsigned short* wrow = wp + ((size_t)t * 128 + a) * IC + kb;
#pragma unroll
        for (int nt = 0; nt < 8; ++nt) {
            bf16x8 B = *(const bf16x8*)(wrow + (size_t)nt * 16 * IC);
#pragma unroll
            for (int i = 0; i < 4; ++i)
                acc[i][nt] = __builtin_amdgcn_mfma_f32_16x16x32_bf16(A[i], B, acc[i][nt], 0, 0, 0);
        }
    }

    float* dst = part + ((size_t)g * 32 + b) * (128 * 196);
#pragma unroll
    for (int i = 0; i < 4; ++i) {
        int m0 = (3 * wv + i) * 16 + kg * 4;
        if (m0 < 196) {
#pragma unroll
            for (int nt = 0; nt < 8; ++nt) {
                int oc = nt * 16 + a;
                *(f32x4*)(dst + (size_t)oc * 196 + m0) = acc[i][nt];
            }
        }
    }
}

// sum 6 partials
__global__ void k_reduce6(const float* __restrict__ part, float* __restrict__ y, int n) {
    int i = blockIdx.x * blockDim.x + threadIdx.x;
    if (i < n) {
        float s = 0.f;
#pragma unroll
        for (int g = 0; g < 6; ++g) s += part[(size_t)g * n + i];
        y[i] = s;
    }
}

// ---------------- fused transpose of 8 [196,196] matrices ----------------
struct P8 { const float* p[8]; };
__global__ void k_transpose8(P8 ws_in, float* __restrict__ wt) {
    int i = blockIdx.x, m = blockIdx.y;
    const float* w = ws_in.p[m];
    float* o = wt + (size_t)m * 38416;
    for (int t = threadIdx.x; t < 196; t += blockDim.x)
        o[(size_t)i * 196 + t] = w[(size_t)t * 196 + i];
}

// ---------------- BN (training mode) ----------------
__global__ void k_bn_stats(const float* __restrict__ y, float* __restrict__ stats,
                           int C) {
    int ch = blockIdx.x; int tid = threadIdx.x;
    float s = 0.f, s2 = 0.f;
    for (int b = 0; b < 32; ++b) {
        const float* p = &y[(size_t)(b * C + ch) * 196];
        for (int i = tid; i < 196; i += 256) { float v = p[i]; s += v; s2 += v * v; }
    }
    __shared__ float r1[4], r2[4];
    for (int sh = 32; sh; sh >>= 1) { s += __shfl_xor(s, sh); s2 += __shfl_xor(s2, sh); }
    if ((tid & 63) == 0) { r1[tid >> 6] = s; r2[tid >> 6] = s2; }
    __syncthreads();
    if (tid == 0) {
        float S = r1[0] + r1[1] + r1[2] + r1[3];
        float S2 = r2[0] + r2[1] + r2[2] + r2[3];
        float m = S / 6272.f;
        float v = S2 / 6272.f - m * m;
        stats[2 * ch] = m;
        stats[2 * ch + 1] = rsqrtf(v + 1e-5f);
    }
}

// optional transposed (fT != nullptr): fT[(b*196+s)*C + ch]
__global__ void k_bn_apply_relu(float* __restrict__ y, const float* __restrict__ stats,
                                const float* __restrict__ g, const float* __restrict__ be,
                                float* __restrict__ fT, int C) {
    int idx = blockIdx.x;           // b*C + ch
    int ch = idx % C, b = idx / C;
    int s = threadIdx.x;
    if (s < 196) {
        float m = stats[2 * ch], r = stats[2 * ch + 1];
        float v = y[(size_t)idx * 196 + s];
        float o = fmaxf((v - m) * r * g[ch] + be[ch], 0.f);
        y[(size_t)idx * 196 + s] = o;
        if (fT) fT[((size_t)b * 196 + s) * C + ch] = o;
    }
}

// ---------------- catnum ----------------
__global__ void k_catnum(const float* __restrict__ inp, int A,
                         const float* __restrict__ w, const float* __restrict__ bias,
                         const float* __restrict__ g, const float* __restrict__ be,
                         float* __restrict__ outv) {
    int j = blockIdx.x;
    int lane = threadIdx.x;
    float v = 0.f;
    if (lane < 32) {
        v = bias[j];
        for (int k = 0; k < A; ++k) v += inp[lane * A + k] * w[j * A + k];
    }
    float s = (lane < 32) ? v : 0.f;
    float s2 = (lane < 32) ? v * v : 0.f;
    for (int m = 16; m; m >>= 1) { s += __shfl_xor(s, m, 32); s2 += __shfl_xor(s2, m, 32); }
    if (lane < 32) {
        float mean = s / 32.f;
        float var = s2 / 32.f - mean * mean;
        float rstd = rsqrtf(var + 1e-5f);
        float t = (v - mean) * rstd * g[j] + be[j];
        t = t / (1.f + expf(-t));
        outv[lane * 196 + j] = t;
    }
}

// text + transposed text
__global__ void k_textbuild(const float* __restrict__ toh, const float* __restrict__ tnm,
                            float* __restrict__ text, float* __restrict__ textT) {
    int idx = blockIdx.x;           // b*45+c
    int b = idx / 45, c = idx - b * 45;
    int s = threadIdx.x;
    if (s < 196) {
        float v = (c < 30) ? toh[b * 196 + s] : tnm[b * 196 + s];
        text[(size_t)idx * 196 + s] = v;
        textT[((size_t)b * 196 + s) * 45 + c] = v;
    }
}

// ---------------- GCN ----------------
template <int C>
__global__ void k_gcn_dist(const float* __restrict__ f, const float* __restrict__ fT,
                           float* __restrict__ dist) {
    int idx = blockIdx.x;           // b*C+i
    int b = idx / C;
    __shared__ float fi[196];
    int tid = threadIdx.x;
    for (int n = tid; n < 196; n += blockDim.x) fi[n] = f[(size_t)idx * 196 + n];
    __syncthreads();
    if (tid < C) {
        const float* ft = fT + (size_t)b * 196 * C + tid;
        float s = 0.f;
#pragma unroll 7
        for (int n = 0; n < 196; ++n) s += fabsf(fi[n] - ft[(size_t)n * C]);
        dist[(size_t)idx * C + tid] = expf(-s);
    }
}

template <int C>
__global__ void k_gcn_spmmfin(const float* __restrict__ dist, const float* __restrict__ f,
                              const float* __restrict__ wt, const float* __restrict__ bias,
                              float* __restrict__ outp) {
    int idx = blockIdx.x;           // b*C+i
    int b = idx / C;
    __shared__ float ds[C];
    __shared__ float ts[196];
    int tid = threadIdx.x;
    for (int j = tid; j < C; j += 256) ds[j] = dist[(size_t)idx * C + j];
    __syncthreads();
    if (tid < 196) {
        float a = 0.f;
#pragma unroll 8
        for (int j = 0; j < C; ++j) a += ds[j] * f[((size_t)b * C + j) * 196 + tid];
        ts[tid] = a;
    }
    __syncthreads();
    if (tid < 196) {
        float a = bias[tid];
#pragma unroll 7
        for (int n = 0; n < 196; ++n) a += ts[n] * wt[n * 196 + tid];
        outp[(size_t)idx * 196 + tid] = fmaxf(a, 0.f) + f[(size_t)idx * 196 + tid];
    }
}

// ---------------- fused LayerNorm + relu(linear), dual-layout q -------------
template <int R>
__global__ void k_lnlin(const float* __restrict__ x, const float* __restrict__ g,
                        const float* __restrict__ be, const float* __restrict__ eT,
                        const float* __restrict__ eb, float* __restrict__ lnout,
                        float* __restrict__ qout, float* __restrict__ qT) {
    int row = blockIdx.x;           // b*R + i
    int b = row / R, i = row - b * R;
    int tid = threadIdx.x;
    __shared__ float ls[196];
    __shared__ float red[8];
    float v = (tid < 196) ? x[(size_t)row * 196 + tid] : 0.f;
    float s = v, s2 = v * v;
    for (int m = 32; m; m >>= 1) { s += __shfl_xor(s, m); s2 += __shfl_xor(s2, m); }
    if ((tid & 63) == 0) { red[tid >> 6] = s; red[4 + (tid >> 6)] = s2; }
    __syncthreads();
    s = red[0] + red[1] + red[2] + red[3];
    s2 = red[4] + red[5] + red[6] + red[7];
    float mean = s / 196.f;
    float var = s2 / 196.f - mean * mean;
    float rstd = rsqrtf(var + 1e-6f);
    if (tid < 196) {
        float l = (v - mean) * rstd * g[tid] + be[tid];
        ls[tid] = l;
        lnout[(size_t)row * 196 + tid] = l;
    }
    __syncthreads();
    if (tid < 196) {
        float acc = eb[tid];
#pragma unroll 7
        for (int n = 0; n < 196; ++n) acc += ls[n] * eT[n * 196 + tid];
        float q = fmaxf(acc, 0.f);
        qout[(size_t)row * 196 + tid] = q;
        qT[((size_t)b * 196 + tid) * R + i] = q;
    }
}

// ---------------- fused cross-attention row (coalesced via qT) --------------
template <int RA, int RB>
__global__ void k_attrow(const float* __restrict__ own, const float* __restrict__ ownT,
                         const float* __restrict__ oth, const float* __restrict__ othT,
                         const float* __restrict__ wAT, const float* __restrict__ bA,
                         const float* __restrict__ wBT, const float* __restrict__ bB,
                         const float* __restrict__ lnres, const float* __restrict__ res2,
                         float* __restrict__ feat, int cbase) {
    int i = blockIdx.x, b = blockIdx.y;
    int tid = threadIdx.x;
    __shared__ float qs[196], sA[RA], sB[RB], fA[196], fB[196];
    __shared__ float red[4];
    const float* ownb = own + (size_t)b * RA * 196;
    const float* othb = oth + (size_t)b * RB * 196;
    for (int n = tid; n < 196; n += 256) qs[n] = ownb[(size_t)i * 196 + n];
    __syncthreads();
    if (tid < RA) {
        const float* ot = ownT + (size_t)b * 196 * RA + tid;
        float a = 0.f;
#pragma unroll 7
        for (int n = 0; n < 196; ++n) a += qs[n] * ot[(size_t)n * RA];
        sA[tid] = a;
    } else if (tid < RA + RB) {
        const float* ot = othT + (size_t)b * 196 * RB + (tid - RA);
        float a = 0.f;
#pragma unroll 7
        for (int n = 0; n < 196; ++n) a += qs[n] * ot[(size_t)n * RB];
        sB[tid - RA] = a;
    }
    __syncthreads();
    float mA = bmax256((tid < RA) ? sA[tid] : -3.4e38f, red, tid);
    float eA = (tid < RA) ? expf(sA[tid] - mA) : 0.f;
    if (tid < RA) sA[tid] = eA;
    float sumA = bsum256(eA, red, tid);
    float mB = bmax256((tid < RB) ? sB[tid] : -3.4e38f, red, tid);
    float eB = (tid < RB) ? expf(sB[tid] - mB) : 0.f;
    if (tid < RB) sB[tid] = eB;
    float sumB = bsum256(eB, red, tid);
    float invA = 1.f / sumA, invB = 1.f / sumB;
    if (tid < 196) {
        float fa = 0.f, fb = 0.f;
#pragma unroll 8
        for (int j = 0; j < RA; ++j) fa += sA[j] * ownb[(size_t)j * 196 + tid];
#pragma unroll 8
        for (int j = 0; j < RB; ++j) fb += sB[j] * othb[(size_t)j * 196 + tid];
        fA[tid] = fa * invA;
        fB[tid] = fb * invB;
    }
    __syncthreads();
    if (tid < 196) {
        size_t rrow = ((size_t)b * RA + i) * 196 + tid;
        float acc = bA[tid] + bB[tid] + lnres[rrow] + res2[rrow];
#pragma unroll 7
        for (int n = 0; n < 196; ++n)
            acc += fA[n] * wAT[n * 196 + tid] + fB[n] * wBT[n * 196 + tid];
        feat[((size_t)b * 173 + cbase + i) * 196 + tid] = acc;
    }
}

// ---------------- 1x1x1 conv; RES=0 writes qT, RES=1 adds res + rowsum ------
template <int RES>
__global__ void k_conv1x1(const float* __restrict__ x, const float* __restrict__ w,
                          const float* __restrict__ bias, const float* __restrict__ res,
                          float* __restrict__ outp, float* __restrict__ aux) {
    int o = blockIdx.x, b = blockIdx.y;
    __shared__ float wsm[173];
    __shared__ float red[4];
    int tid = threadIdx.x;
    for (int c = tid; c < 173; c += 256) wsm[c] = w[o * 173 + c];
    __syncthreads();
    float val = 0.f;
    if (tid < 196) {
        float acc = bias[o];
#pragma unroll 8
        for (int c = 0; c < 173; ++c) acc += wsm[c] * x[(size_t)(b * 173 + c) * 196 + tid];
        acc = fmaxf(acc, 0.f);
        if (RES) acc += res[(size_t)(b * 173 + o) * 196 + tid];
        val = acc;
        outp[(size_t)(b * 173 + o) * 196 + tid] = acc;
        if (!RES) aux[((size_t)b * 196 + tid) * 173 + o] = acc;   // qT
    }
    if (RES) {
        float s = bsum256(val, red, tid);                          // rowsum
        if (tid == 0) aux[(size_t)b * 173 + o] = s;
    }
}

// ---------------- CMSA attention (writes A^T) ----------------
__global__ void k_cmsa_att(const float* __restrict__ q, const float* __restrict__ qT,
                           float* __restrict__ AT) {
    int i = blockIdx.x, b = blockIdx.y;   // i in [0,196)
    __shared__ float col[173];
    __shared__ float red[4];
    int tid = threadIdx.x;
    if (tid < 173) col[tid] = qT[((size_t)b * 196 + i) * 173 + tid];
    __syncthreads();
    float sc = -3.4e38f;
    if (tid < 196) {
        float acc = 0.f;
#pragma unroll 8
        for (int c = 0; c < 173; ++c) acc += col[c] * q[(size_t)(b * 173 + c) * 196 + tid];
        sc = acc;
    }
    float m = bmax256(sc, red, tid);
    float e = (tid < 196) ? expf(sc - m) : 0.f;
    float s = bsum256(e, red, tid);
    // AT[j][i] = A[i][j]; here row index of A is i, col is tid=j.
    if (tid < 196) AT[((size_t)b * 196 + tid) * 196 + i] = e / s;
}

__global__ void k_cmsa_apply(const float* __restrict__ AT, const float* __restrict__ q,
                             float* __restrict__ fea) {
    int c = blockIdx.x, b = blockIdx.y;
    __shared__ float qs[196];
    int tid = threadIdx.x;
    for (int n = tid; n < 196; n += 256) qs[n] = q[(size_t)(b * 173 + c) * 196 + n];
    __syncthreads();
    if (tid < 196) {
        float acc = 0.f;
        const float* at = AT + (size_t)b * 196 * 196 + tid;
#pragma unroll 7
        for (int j = 0; j < 196; ++j) acc += at[(size_t)j * 196] * qs[j];
        fea[(size_t)(b * 173 + c) * 196 + tid] = acc;
    }
}

// ---------------- final classifier (pcm precomputed) ----------------
__global__ void k_finale(const float* __restrict__ toh, const float* __restrict__ tnm,
                         const float* __restrict__ rowsum, const float* __restrict__ cls_w,
                         const float* __restrict__ cls_b, float* __restrict__ out) {
    int b = blockIdx.x;
    __shared__ float r1[4], r2[4];
    int tid = threadIdx.x;
    float a = (tid < 196) ? toh[b * 196 + tid] : 0.f;
    float c = (tid < 196) ? tnm[b * 196 + tid] : 0.f;
    for (int sh = 32; sh; sh >>= 1) { a += __shfl_xor(a, sh); c += __shfl_xor(c, sh); }
    if ((tid & 63) == 0) { r1[tid >> 6] = a; r2[tid >> 6] = c; }
    __syncthreads();
    if (tid < 2) {
        float soh = r1[0] + r1[1] + r1[2] + r1[3];
        float snm = r2[0] + r2[1] + r2[2] + r2[3];
        const float* wrow = &cls_w[tid * 218];
        float acc = cls_b[tid];
        float w1 = 0.f, w2 = 0.f;
        for (int k = 0; k < 30; ++k) w1 += wrow[k];
        for (int k = 30; k < 45; ++k) w2 += wrow[k];
        acc += soh * w1 + snm * w2;
        for (int k = 0; k < 173; ++k) acc += wrow[45 + k] * rowsum[(size_t)b * 173 + k];
        out[b * 2 + tid] = acc;
    }
}

// ---------------------------------------------------------------------------
extern "C" void kernel_launch(void* const* d_in, const int* in_sizes, int n_in,
                              void* d_out, int out_size, void* d_ws, size_t ws_size,
                              hipStream_t stream) {
    const float* x      = (const float*)d_in[0];
    const float* oneHot = (const float*)d_in[1];
    const float* num    = (const float*)d_in[2];
    const float* c1_w1  = (const float*)d_in[3];
    const float* c1_g1  = (const float*)d_in[5];
    const float* c1_be1 = (const float*)d_in[6];
    const float* c1_w2  = (const float*)d_in[7];
    const float* c1_g2  = (const float*)d_in[9];
    const float* c1_be2 = (const float*)d_in[10];
    const float* oh_w   = (const float*)d_in[11];
    const float* oh_b   = (const float*)d_in[12];
    const float* oh_g   = (const float*)d_in[13];
    const float* oh_be  = (const float*)d_in[14];
    const float* nm_w   = (const float*)d_in[15];
    const float* nm_b   = (const float*)d_in[16];
    const float* nm_g   = (const float*)d_in[17];
    const float* nm_be  = (const float*)d_in[18];
    const float* gm1_w  = (const float*)d_in[19];
    const float* gm1_b  = (const float*)d_in[20];
    const float* gm2_w  = (const float*)d_in[21];
    const float* gm2_b  = (const float*)d_in[22];
    const float* ln1_g  = (const float*)d_in[23];
    const float* ln1_b  = (const float*)d_in[24];
    const float* ln2_g  = (const float*)d_in[25];
    const float* ln2_b  = (const float*)d_in[26];
    const float* e1_w   = (const float*)d_in[27];
    const float* e1_b   = (const float*)d_in[28];
    const float* e2_w   = (const float*)d_in[29];
    const float* e2_b   = (const float*)d_in[30];
    const float* f1_w   = (const float*)d_in[31];
    const float* f1_b   = (const float*)d_in[32];
    const float* f2_w   = (const float*)d_in[33];
    const float* f2_b   = (const float*)d_in[34];
    const float* f3_w   = (const float*)d_in[35];
    const float* f3_b   = (const float*)d_in[36];
    const float* f4_w   = (const float*)d_in[37];
    const float* f4_b   = (const float*)d_in[38];
    const float* cm_w   = (const float*)d_in[39];
    const float* cm_b   = (const float*)d_in[40];
    const float* cmf_w  = (const float*)d_in[41];
    const float* cmf_b  = (const float*)d_in[42];
    const float* cls_w  = (const float*)d_in[43];
    const float* cls_b  = (const float*)d_in[44];
    float* out = (float*)d_out;
    float* W = (float*)d_ws;

    // ---- workspace layout (floats) ----
    const size_t L = 802816;    // 32*128*196
    const size_t T = 282240;    // 32*45*196
    const size_t F3 = 1085056;  // 32*173*196
    const size_t S2 = 1229312;  // 32*196*196
    const size_t o_A    = 0;
    const size_t o_B    = L;
    const size_t o_C    = 2 * L;
    const size_t o_part = 3 * L;          // conv partials [3L, 9L)
    const size_t o_iq   = 3 * L;
    const size_t o_tq   = 4 * L;
    const size_t o_t1   = 4 * L + T;
    const size_t o_t3   = 4 * L + 2 * T;
    const size_t o_ln2  = 4 * L + 3 * T;
    const size_t o_toh  = 4 * L + 4 * T;
    const size_t o_tnm  = o_toh + 6272;
    const size_t o_st   = o_tnm + 6272;
    const size_t o_wT   = o_st + 1024;
    const size_t o_feat = o_wT + 8 * 38416;
    const size_t o_q    = o_feat + F3;
    const size_t o_fea  = o_q + F3;
    const size_t o_Acm  = o_fea + F3;     // A^T [32,196,196]; gcn dists earlier
    const size_t o_d1   = o_Acm;
    const size_t o_d2   = o_Acm + 524288;
    // conv-phase-only buffers:
    const size_t o_xt1 = 9 * L;
    const size_t o_xt2 = o_xt1 + 1091584;
    const size_t o_wp1 = o_xt2 + 452608;
    const size_t o_wp2 = o_wp1 + 552960;  // ends 9,543,680
    // transposed-twin region (phase-multiplexed):
    //   gcn phase:  fTimg [32,196,128] at o_tr ; fTtxt [32,196,45] at o_tr+L
    //   att phase:  iqT at o_tr ; tqT at o_tr+L
    //   cmsa phase: qT  [32,196,173] at o_tr (F3)
    const size_t o_tr  = 9543680;
    const size_t o_rs  = o_tr + F3;       // rowsum 32*173
    // end = 10,634,272 floats = 42.5 MB

    float* part = W + o_part;
    unsigned short* xt1 = (unsigned short*)(W + o_xt1);
    unsigned short* xt2 = (unsigned short*)(W + o_xt2);
    unsigned short* wp1 = (unsigned short*)(W + o_wp1);
    unsigned short* wp2 = (unsigned short*)(W + o_wp2);
    float* gm1T = W + o_wT + 0 * 38416;
    float* gm2T = W + o_wT + 1 * 38416;
    float* e1T  = W + o_wT + 2 * 38416;
    float* e2T  = W + o_wT + 3 * 38416;
    float* f1T  = W + o_wT + 4 * 38416;
    float* f2T  = W + o_wT + 5 * 38416;
    float* f3T  = W + o_wT + 6 * 38416;
    float* f4T  = W + o_wT + 7 * 38416;

    hipFuncSetAttribute((const void*)&k_convmfma<320, 328, 45, 10>,
                        hipFuncAttributeMaxDynamicSharedMemorySize, 208 * 328 * 2);
    hipFuncSetAttribute((const void*)&k_convmfma<128, 136, 18, 4>,
                        hipFuncAttributeMaxDynamicSharedMemorySize, 208 * 136 * 2);

    // ---- conv prep ----
    k_wpack<<<(27 * 128 * 40 + 255) / 256, 256, 0, stream>>>(c1_w1, wp1, 320);
    k_wpack<<<(27 * 128 * 16 + 255) / 256, 256, 0, stream>>>(c1_w2, wp2, 128);
    k_xt<<<dim3((208 * 164 + 255) / 256, 32), 256, 0, stream>>>(x, xt1, 320, 328);

    // ---- conv1 + reduce + BN + relu -> A ----
    k_convmfma<320, 328, 45, 10><<<dim3(6, 32), 256, 208 * 328 * 2, stream>>>(xt1, wp1, part);
    k_reduce6<<<3136, 256, 0, stream>>>(part, W + o_A, 802816);
    k_bn_stats<<<128, 256, 0, stream>>>(W + o_A, W + o_st, 128);
    k_bn_apply_relu<<<4096, 256, 0, stream>>>(W + o_A, W + o_st, c1_g1, c1_be1, nullptr, 128);

    // ---- conv2 + reduce + BN + relu -> conv5(f) in B (+ fTimg) ----
    k_xt<<<dim3((208 * 68 + 255) / 256, 32), 256, 0, stream>>>(W + o_A, xt2, 128, 136);
    k_convmfma<128, 136, 18, 4><<<dim3(6, 32), 256, 208 * 136 * 2, stream>>>(xt2, wp2, part);
    k_reduce6<<<3136, 256, 0, stream>>>(part, W + o_B, 802816);
    k_bn_stats<<<128, 256, 0, stream>>>(W + o_B, W + o_st + 512, 128);
    k_bn_apply_relu<<<4096, 256, 0, stream>>>(W + o_B, W + o_st + 512, c1_g2, c1_be2,
                                              W + o_tr, 128);

    // ---- weight transposes ----
    P8 p8;
    p8.p[0] = gm1_w; p8.p[1] = gm2_w; p8.p[2] = e1_w; p8.p[3] = e2_w;
    p8.p[4] = f1_w;  p8.p[5] = f2_w;  p8.p[6] = f3_w; p8.p[7] = f4_w;
    k_transpose8<<<dim3(196, 8), 256, 0, stream>>>(p8, W + o_wT);

    // ---- catnum -> toh,tnm ; text (+T) -> t1 ----
    k_catnum<<<196, 64, 0, stream>>>(oneHot, 24, oh_w, oh_b, oh_g, oh_be, W + o_toh);
    k_catnum<<<196, 64, 0, stream>>>(num, 11, nm_w, nm_b, nm_g, nm_be, W + o_tnm);
    k_textbuild<<<32 * 45, 256, 0, stream>>>(W + o_toh, W + o_tnm, W + o_t1, W + o_tr + L);

    // ---- GCN img ----
    k_gcn_dist<128><<<4096, 128, 0, stream>>>(W + o_B, W + o_tr, W + o_d1);
    k_gcn_spmmfin<128><<<4096, 256, 0, stream>>>(W + o_d1, W + o_B, gm1T, gm1_b, W + o_C);

    // ---- GCN text ----
    k_gcn_dist<45><<<1440, 64, 0, stream>>>(W + o_t1, W + o_tr + L, W + o_d2);
    k_gcn_spmmfin<45><<<1440, 256, 0, stream>>>(W + o_d2, W + o_t1, gm2T, gm2_b, W + o_t3);

    // ---- LN + q projections (dual layout) ----
    k_lnlin<128><<<4096, 256, 0, stream>>>(W + o_C, ln1_g, ln1_b, e1T, e1_b,
                                           W + o_B, W + o_iq, W + o_tr);
    k_lnlin<45><<<1440, 256, 0, stream>>>(W + o_t3, ln2_g, ln2_b, e2T, e2_b,
                                          W + o_ln2, W + o_tq, W + o_tr + L);

    // ---- fused cross-attention -> feat ----
    k_attrow<128, 45><<<dim3(128, 32), 256, 0, stream>>>(
        W + o_iq, W + o_tr, W + o_tq, W + o_tr + L,
        f1T, f1_b, f3T, f3_b, W + o_B, W + o_C, W + o_feat, 0);
    k_attrow<45, 128><<<dim3(45, 32), 256, 0, stream>>>(
        W + o_tq, W + o_tr + L, W + o_iq, W + o_tr,
        f2T, f2_b, f4T, f4_b, W + o_ln2, W + o_t3, W + o_feat, 128);

    // ---- CMSA ----
    k_conv1x1<0><<<dim3(173, 32), 256, 0, stream>>>(W + o_feat, cm_w, cm_b, nullptr,
                                                    W + o_q, W + o_tr);
    k_cmsa_att<<<dim3(196, 32), 256, 0, stream>>>(W + o_q, W + o_tr, W + o_Acm);
    k_cmsa_apply<<<dim3(173, 32), 256, 0, stream>>>(W + o_Acm, W + o_q, W + o_fea);
    k_conv1x1<1><<<dim3(173, 32), 256, 0, stream>>>(W + o_fea, cmf_w, cmf_b, W + o_feat,
                                                    W + o_q, W + o_rs);

    // ---- final classifier ----
    k_finale<<<32, 256, 0, stream>>>(W + o_toh, W + o_tnm, W + o_rs, cls_w, cls_b, out);
}

// Round 7
// 606.303 us; speedup vs baseline: 3.9614x; 1.1372x over previous
//
#include <hip/hip_runtime.h>
#include <hip/hip_bf16.h>

// ---------------------------------------------------------------------------
// mv3Dunet_down_text_cmsa forward. Round 7: MFMA convs + multi-row-blocked
// tail (ROWS outputs per block; shared panels read once per block; wave-level
// softmax/LN reductions). All tail math fp32.
// ---------------------------------------------------------------------------

using bf16x8 = __attribute__((ext_vector_type(8))) short;
using f32x4  = __attribute__((ext_vector_type(4))) float;

__device__ __forceinline__ unsigned short f2bf(float f) {
    unsigned int u = __float_as_uint(f);
    u += 0x7FFFu + ((u >> 16) & 1u);
    return (unsigned short)(u >> 16);
}

// in-place softmax over s[0..len) using one wave's 64 lanes
__device__ __forceinline__ void softseg(float* s, int len, int lane) {
    float m = -3.4e38f;
    for (int j = lane; j < len; j += 64) m = fmaxf(m, s[j]);
    for (int sh = 32; sh; sh >>= 1) m = fmaxf(m, __shfl_xor(m, sh));
    float sum = 0.f;
    for (int j = lane; j < len; j += 64) { float e = expf(s[j] - m); s[j] = e; sum += e; }
    for (int sh = 32; sh; sh >>= 1) sum += __shfl_xor(sum, sh);
    float inv = 1.f / sum;
    for (int j = lane; j < len; j += 64) s[j] *= inv;
}

__device__ __forceinline__ float bsum256(float v, volatile float* red, int tid) {
    for (int sh = 32; sh; sh >>= 1) v += __shfl_xor(v, sh);
    __syncthreads();
    if ((tid & 63) == 0) red[tid >> 6] = v;
    __syncthreads();
    return red[0] + red[1] + red[2] + red[3];
}

// ---------------- X transpose + bf16 cast ----------------
__global__ void k_xt(const float* __restrict__ x, unsigned short* __restrict__ xt,
                     int IC, int ICPAD) {
    int b = blockIdx.y;
    int halfpad = ICPAD >> 1;
    int idx = blockIdx.x * 256 + threadIdx.x;
    if (idx >= 208 * halfpad) return;
    int s = idx / halfpad, icp = idx - s * halfpad;
    int ic = icp * 2;
    unsigned int lo = 0, hi = 0;
    if (s < 196 && ic < IC)     lo = f2bf(x[((size_t)b * IC + ic) * 196 + s]);
    if (s < 196 && ic + 1 < IC) hi = f2bf(x[((size_t)b * IC + ic + 1) * 196 + s]);
    ((unsigned int*)xt)[(size_t)b * 208 * halfpad + idx] = lo | (hi << 16);
}

// ---------------- weight pack ----------------
__global__ void k_wpack(const float* __restrict__ w, unsigned short* __restrict__ wp,
                        int IC) {
    int nc = IC >> 3;
    int idx = blockIdx.x * 256 + threadIdx.x;
    if (idx >= 27 * 128 * nc) return;
    int c = idx % nc; int r = idx / nc; int oc = r & 127; int t = r >> 7;
    const float* ws = w + ((size_t)oc * IC + c * 8) * 27 + t;
    unsigned int o0 = f2bf(ws[0])   | ((unsigned int)f2bf(ws[27])  << 16);
    unsigned int o1 = f2bf(ws[54])  | ((unsigned int)f2bf(ws[81])  << 16);
    unsigned int o2 = f2bf(ws[108]) | ((unsigned int)f2bf(ws[135]) << 16);
    unsigned int o3 = f2bf(ws[162]) | ((unsigned int)f2bf(ws[189]) << 16);
    uint4 v; v.x = o0; v.y = o1; v.z = o2; v.w = o3;
    ((uint4*)wp)[idx] = v;
}

// ---------------- MFMA conv: 27 shifted GEMMs ----------------
template <int IC, int ICPAD, int NU, int KKPT>
__global__ __launch_bounds__(256, 1) void k_convmfma(
    const unsigned short* __restrict__ xt, const unsigned short* __restrict__ wp,
    float* __restrict__ part) {
    extern __shared__ char smem_c[];
    const int tid = threadIdx.x;
    const int g = blockIdx.x, b = blockIdx.y;
    {
        const bf16x8* s8 = (const bf16x8*)(xt + (size_t)b * 208 * ICPAD);
        bf16x8* d8 = (bf16x8*)smem_c;
        for (int c = tid; c < 208 * ICPAD / 8; c += 256) d8[c] = s8[c];
    }
    __syncthreads();
    const int lane = tid & 63;
    const int wv = tid >> 6;
    const int a = lane & 15, kg = lane >> 4;
    int md[4], mh[4], mw[4];
#pragma unroll
    for (int i = 0; i < 4; ++i) {
        int m = (3 * wv + i) * 16 + a;
        md[i] = m / 49; int rr = m - md[i] * 49;
        mh[i] = rr / 7; mw[i] = rr - mh[i] * 7;
    }
    f32x4 acc[4][8];
#pragma unroll
    for (int i = 0; i < 4; ++i)
#pragma unroll
        for (int nt = 0; nt < 8; ++nt) acc[i][nt] = (f32x4){0.f, 0.f, 0.f, 0.f};
    const bf16x8 zv = {0, 0, 0, 0, 0, 0, 0, 0};
    int rsrc[4]; bool ok[4];
    int tcur = -1;
    for (int u = g * NU; u < (g + 1) * NU; ++u) {
        int t = u / KKPT, kk = u - t * KKPT;
        if (t != tcur) {
            tcur = t;
            int kd = t / 9, kh = (t / 3) % 3, kw = t % 3;
#pragma unroll
            for (int i = 0; i < 4; ++i) {
                int d2 = md[i] + kd - 1, h2 = mh[i] + kh - 1, w2 = mw[i] + kw - 1;
                ok[i] = ((unsigned)d2 < 4u) & ((unsigned)h2 < 7u) & ((unsigned)w2 < 7u);
                rsrc[i] = ok[i] ? (d2 * 49 + h2 * 7 + w2) : 0;
            }
        }
        int kb = kk * 32 + kg * 8;
        bf16x8 A[4];
#pragma unroll
        for (int i = 0; i < 4; ++i) {
            bf16x8 v = *(const bf16x8*)(smem_c + ((size_t)rsrc[i] * ICPAD + kb) * 2);
            A[i] = ok[i] ? v : zv;
        }
        const unsigned short* wrow = wp + ((size_t)t * 128 + a) * IC + kb;
#pragma unroll
        for (int nt = 0; nt < 8; ++nt) {
            bf16x8 B = *(const bf16x8*)(wrow + (size_t)nt * 16 * IC);
#pragma unroll
            for (int i = 0; i < 4; ++i)
                acc[i][nt] = __builtin_amdgcn_mfma_f32_16x16x32_bf16(A[i], B, acc[i][nt], 0, 0, 0);
        }
    }
    float* dst = part + ((size_t)g * 32 + b) * (128 * 196);
#pragma unroll
    for (int i = 0; i < 4; ++i) {
        int m0 = (3 * wv + i) * 16 + kg * 4;
        if (m0 < 196) {
#pragma unroll
            for (int nt = 0; nt < 8; ++nt) {
                int oc = nt * 16 + a;
                *(f32x4*)(dst + (size_t)oc * 196 + m0) = acc[i][nt];
            }
        }
    }
}

__global__ void k_reduce6(const float* __restrict__ part, float* __restrict__ y, int n) {
    int i = blockIdx.x * blockDim.x + threadIdx.x;
    if (i < n) {
        float s = 0.f;
#pragma unroll
        for (int g = 0; g < 6; ++g) s += part[(size_t)g * n + i];
        y[i] = s;
    }
}

// ---------------- transpose of 8 [196,196] matrices ----------------
struct P8 { const float* p[8]; };
__global__ void k_transpose8(P8 ws_in, float* __restrict__ wt) {
    int i = blockIdx.x, m = blockIdx.y;
    const float* w = ws_in.p[m];
    float* o = wt + (size_t)m * 38416;
    for (int t = threadIdx.x; t < 196; t += blockDim.x)
        o[(size_t)i * 196 + t] = w[(size_t)t * 196 + i];
}

// ---------------- BN ----------------
__global__ void k_bn_stats(const float* __restrict__ y, float* __restrict__ stats,
                           int C) {
    int ch = blockIdx.x; int tid = threadIdx.x;
    float s = 0.f, s2 = 0.f;
    for (int b = 0; b < 32; ++b) {
        const float* p = &y[(size_t)(b * C + ch) * 196];
        for (int i = tid; i < 196; i += 256) { float v = p[i]; s += v; s2 += v * v; }
    }
    __shared__ float r1[4], r2[4];
    for (int sh = 32; sh; sh >>= 1) { s += __shfl_xor(s, sh); s2 += __shfl_xor(s2, sh); }
    if ((tid & 63) == 0) { r1[tid >> 6] = s; r2[tid >> 6] = s2; }
    __syncthreads();
    if (tid == 0) {
        float S = r1[0] + r1[1] + r1[2] + r1[3];
        float S2 = r2[0] + r2[1] + r2[2] + r2[3];
        float m = S / 6272.f;
        float v = S2 / 6272.f - m * m;
        stats[2 * ch] = m;
        stats[2 * ch + 1] = rsqrtf(v + 1e-5f);
    }
}

__global__ void k_bn_apply_relu(float* __restrict__ y, const float* __restrict__ stats,
                                const float* __restrict__ g, const float* __restrict__ be,
                                float* __restrict__ fT, int C) {
    int idx = blockIdx.x;
    int ch = idx % C, b = idx / C;
    int s = threadIdx.x;
    if (s < 196) {
        float m = stats[2 * ch], r = stats[2 * ch + 1];
        float v = y[(size_t)idx * 196 + s];
        float o = fmaxf((v - m) * r * g[ch] + be[ch], 0.f);
        y[(size_t)idx * 196 + s] = o;
        if (fT) fT[((size_t)b * 196 + s) * C + ch] = o;
    }
}

// ---------------- catnum ----------------
__global__ void k_catnum(const float* __restrict__ inp, int A,
                         const float* __restrict__ w, const float* __restrict__ bias,
                         const float* __restrict__ g, const float* __restrict__ be,
                         float* __restrict__ outv) {
    int j = blockIdx.x;
    int lane = threadIdx.x;
    float v = 0.f;
    if (lane < 32) {
        v = bias[j];
        for (int k = 0; k < A; ++k) v += inp[lane * A + k] * w[j * A + k];
    }
    float s = (lane < 32) ? v : 0.f;
    float s2 = (lane < 32) ? v * v : 0.f;
    for (int m = 16; m; m >>= 1) { s += __shfl_xor(s, m, 32); s2 += __shfl_xor(s2, m, 32); }
    if (lane < 32) {
        float mean = s / 32.f;
        float var = s2 / 32.f - mean * mean;
        float rstd = rsqrtf(var + 1e-5f);
        float t = (v - mean) * rstd * g[j] + be[j];
        t = t / (1.f + expf(-t));
        outv[lane * 196 + j] = t;
    }
}

__global__ void k_textbuild(const float* __restrict__ toh, const float* __restrict__ tnm,
                            float* __restrict__ text, float* __restrict__ textT) {
    int idx = blockIdx.x;
    int b = idx / 45, c = idx - b * 45;
    int s = threadIdx.x;
    if (s < 196) {
        float v = (c < 30) ? toh[b * 196 + s] : tnm[b * 196 + s];
        text[(size_t)idx * 196 + s] = v;
        textT[((size_t)b * 196 + s) * 45 + c] = v;
    }
}

// ---------------- GCN dist (multi-row) ----------------
template <int C, int ROWS>
__global__ void k_gcn_dist_t(const float* __restrict__ f, const float* __restrict__ fT,
                             float* __restrict__ dist) {
    __shared__ float fi[ROWS][196];
    const int i0 = blockIdx.x * ROWS, b = blockIdx.y;
    const int tid = threadIdx.x;
    for (int idx = tid; idx < ROWS * 196; idx += 256) {
        int r = idx / 196, n = idx - r * 196;
        fi[r][n] = f[((size_t)(b * C + i0 + r)) * 196 + n];
    }
    __syncthreads();
    if (tid < C) {
        const float* ft = fT + (size_t)b * 196 * C + tid;
        float a[ROWS];
#pragma unroll
        for (int r = 0; r < ROWS; ++r) a[r] = 0.f;
        for (int n = 0; n < 196; ++n) {
            float v = ft[(size_t)n * C];
#pragma unroll
            for (int r = 0; r < ROWS; ++r) a[r] += fabsf(fi[r][n] - v);
        }
#pragma unroll
        for (int r = 0; r < ROWS; ++r)
            dist[((size_t)(b * C + i0 + r)) * C + tid] = expf(-a[r]);
    }
}

// ---------------- GCN spmm+fin (multi-row) ----------------
template <int C, int ROWS>
__global__ void k_gcn_spmmfin_t(const float* __restrict__ dist, const float* __restrict__ f,
                                const float* __restrict__ wt, const float* __restrict__ bias,
                                float* __restrict__ outp) {
    __shared__ float ds[ROWS][C];
    __shared__ float ts[ROWS][196];
    const int i0 = blockIdx.x * ROWS, b = blockIdx.y;
    const int tid = threadIdx.x;
    for (int idx = tid; idx < ROWS * C; idx += 256) {
        int r = idx / C, j = idx - r * C;
        ds[r][j] = dist[((size_t)(b * C + i0 + r)) * C + j];
    }
    __syncthreads();
    if (tid < 196) {
        float a[ROWS];
#pragma unroll
        for (int r = 0; r < ROWS; ++r) a[r] = 0.f;
        for (int j = 0; j < C; ++j) {
            float v = f[((size_t)b * C + j) * 196 + tid];
#pragma unroll
            for (int r = 0; r < ROWS; ++r) a[r] += ds[r][j] * v;
        }
#pragma unroll
        for (int r = 0; r < ROWS; ++r) ts[r][tid] = a[r];
    }
    __syncthreads();
    if (tid < 196) {
        float a[ROWS];
        float bi = bias[tid];
#pragma unroll
        for (int r = 0; r < ROWS; ++r) a[r] = bi;
        for (int n = 0; n < 196; ++n) {
            float wv = wt[(size_t)n * 196 + tid];
#pragma unroll
            for (int r = 0; r < ROWS; ++r) a[r] += ts[r][n] * wv;
        }
#pragma unroll
        for (int r = 0; r < ROWS; ++r) {
            size_t rr = ((size_t)(b * C + i0 + r)) * 196 + tid;
            outp[rr] = fmaxf(a[r], 0.f) + f[rr];
        }
    }
}

// ---------------- LN + relu(linear), multi-row, dual-layout q ----------------
template <int R, int ROWS>
__global__ void k_lnlin_t(const float* __restrict__ x, const float* __restrict__ g,
                          const float* __restrict__ be, const float* __restrict__ eT,
                          const float* __restrict__ eb, float* __restrict__ lnout,
                          float* __restrict__ qout, float* __restrict__ qT) {
    __shared__ float ls[ROWS][196];
    const int i0 = blockIdx.x * ROWS, b = blockIdx.y;
    const int tid = threadIdx.x;
    const int wv = tid >> 6, lane = tid & 63;
    for (int idx = tid; idx < ROWS * 196; idx += 256) {
        int r = idx / 196, n = idx - r * 196;
        ls[r][n] = x[((size_t)(b * R + i0 + r)) * 196 + n];
    }
    __syncthreads();
    for (int k = 0;; ++k) {
        int r = wv + 4 * k;
        if (r >= ROWS) break;
        float s = 0.f, s2 = 0.f;
        for (int j = lane; j < 196; j += 64) { float v = ls[r][j]; s += v; s2 += v * v; }
        for (int sh = 32; sh; sh >>= 1) { s += __shfl_xor(s, sh); s2 += __shfl_xor(s2, sh); }
        float mean = s / 196.f;
        float var = s2 / 196.f - mean * mean;
        float rstd = rsqrtf(var + 1e-6f);
        size_t rowo = ((size_t)(b * R + i0 + r)) * 196;
        for (int j = lane; j < 196; j += 64) {
            float l = (ls[r][j] - mean) * rstd * g[j] + be[j];
            ls[r][j] = l;
            lnout[rowo + j] = l;
        }
    }
    __syncthreads();
    if (tid < 196) {
        float a[ROWS];
        float bi = eb[tid];
#pragma unroll
        for (int r = 0; r < ROWS; ++r) a[r] = bi;
        for (int n = 0; n < 196; ++n) {
            float ev = eT[(size_t)n * 196 + tid];
#pragma unroll
            for (int r = 0; r < ROWS; ++r) a[r] += ls[r][n] * ev;
        }
#pragma unroll
        for (int r = 0; r < ROWS; ++r) {
            float q = fmaxf(a[r], 0.f);
            qout[((size_t)(b * R + i0 + r)) * 196 + tid] = q;
            qT[((size_t)b * 196 + tid) * R + i0 + r] = q;
        }
    }
}

// ---------------- fused cross-attention, multi-row ----------------
template <int ROWS, int RA, int RB>
__global__ void k_attrow_t(const float* __restrict__ own, const float* __restrict__ ownT,
                           const float* __restrict__ oth, const float* __restrict__ othT,
                           const float* __restrict__ wAT, const float* __restrict__ bA,
                           const float* __restrict__ wBT, const float* __restrict__ bB,
                           const float* __restrict__ lnres, const float* __restrict__ res2,
                           float* __restrict__ feat, int cbase) {
    __shared__ float buf1[ROWS][196];      // qs -> fA
    __shared__ float sc[ROWS][176];        // scores -> probs (RA+RB=173)
    __shared__ float fB[ROWS][196];
    const int i0 = blockIdx.x * ROWS, b = blockIdx.y;
    const int tid = threadIdx.x;
    const int wv = tid >> 6, lane = tid & 63;
    const float* ownb = own + (size_t)b * RA * 196;
    const float* othb = oth + (size_t)b * RB * 196;
    for (int idx = tid; idx < ROWS * 196; idx += 256) {
        int r = idx / 196, n = idx - r * 196;
        buf1[r][n] = ownb[(size_t)(i0 + r) * 196 + n];
    }
    __syncthreads();
    if (tid < RA) {
        const float* ot = ownT + (size_t)b * 196 * RA + tid;
        float a[ROWS];
#pragma unroll
        for (int r = 0; r < ROWS; ++r) a[r] = 0.f;
        for (int n = 0; n < 196; ++n) {
            float kv = ot[(size_t)n * RA];
#pragma unroll
            for (int r = 0; r < ROWS; ++r) a[r] += buf1[r][n] * kv;
        }
#pragma unroll
        for (int r = 0; r < ROWS; ++r) sc[r][tid] = a[r];
    } else if (tid < RA + RB) {
        const float* ot = othT + (size_t)b * 196 * RB + (tid - RA);
        float a[ROWS];
#pragma unroll
        for (int r = 0; r < ROWS; ++r) a[r] = 0.f;
        for (int n = 0; n < 196; ++n) {
            float kv = ot[(size_t)n * RB];
#pragma unroll
            for (int r = 0; r < ROWS; ++r) a[r] += buf1[r][n] * kv;
        }
#pragma unroll
        for (int r = 0; r < ROWS; ++r) sc[r][tid] = a[r];
    }
    __syncthreads();
    for (int k = 0;; ++k) {
        int r = wv + 4 * k;
        if (r >= ROWS) break;
        softseg(&sc[r][0], RA, lane);
        softseg(&sc[r][RA], RB, lane);
    }
    __syncthreads();
    if (tid < 196) {
        float a[ROWS];
#pragma unroll
        for (int r = 0; r < ROWS; ++r) a[r] = 0.f;
        for (int j = 0; j < RA; ++j) {
            float v = ownb[(size_t)j * 196 + tid];
#pragma unroll
            for (int r = 0; r < ROWS; ++r) a[r] += sc[r][j] * v;
        }
        float c[ROWS];
#pragma unroll
        for (int r = 0; r < ROWS; ++r) c[r] = 0.f;
        for (int j = 0; j < RB; ++j) {
            float v = othb[(size_t)j * 196 + tid];
#pragma unroll
            for (int r = 0; r < ROWS; ++r) c[r] += sc[r][RA + j] * v;
        }
#pragma unroll
        for (int r = 0; r < ROWS; ++r) { buf1[r][tid] = a[r]; fB[r][tid] = c[r]; }
    }
    __syncthreads();
    if (tid < 196) {
        float a[ROWS];
        float bb = bA[tid] + bB[tid];
#pragma unroll
        for (int r = 0; r < ROWS; ++r) {
            size_t rr = ((size_t)(b * RA + i0 + r)) * 196 + tid;
            a[r] = bb + lnres[rr] + res2[rr];
        }
        for (int n = 0; n < 196; ++n) {
            float wa = wAT[(size_t)n * 196 + tid];
            float wb = wBT[(size_t)n * 196 + tid];
#pragma unroll
            for (int r = 0; r < ROWS; ++r) a[r] += buf1[r][n] * wa + fB[r][n] * wb;
        }
#pragma unroll
        for (int r = 0; r < ROWS; ++r)
            feat[((size_t)(b * 173 + cbase + i0 + r)) * 196 + tid] = a[r];
    }
}

// ---------------- 1x1 conv, multi-row; RES=0 writes qT, RES=1 res+rowsum ----
template <int RES, int ROWS>
__global__ void k_conv1x1_t(const float* __restrict__ x, const float* __restrict__ w,
                            const float* __restrict__ bias, const float* __restrict__ res,
                            float* __restrict__ outp, float* __restrict__ aux) {
    __shared__ float wsm[ROWS][173];
    __shared__ float vals[RES ? ROWS : 1][200];
    const int o0 = blockIdx.x * ROWS, b = blockIdx.y;
    const int tid = threadIdx.x;
    const int nv = (173 - o0 < ROWS) ? (173 - o0) : ROWS;
    for (int idx = tid; idx < nv * 173; idx += 256) {
        int r = idx / 173, c = idx - r * 173;
        wsm[r][c] = w[(size_t)(o0 + r) * 173 + c];
    }
    __syncthreads();
    if (tid < 196) {
        float a[ROWS];
#pragma unroll
        for (int r = 0; r < ROWS; ++r) a[r] = (r < nv) ? bias[o0 + r] : 0.f;
        for (int c = 0; c < 173; ++c) {
            float xv = x[((size_t)(b * 173 + c)) * 196 + tid];
#pragma unroll
            for (int r = 0; r < ROWS; ++r) a[r] += wsm[r][c] * xv;
        }
#pragma unroll
        for (int r = 0; r < ROWS; ++r) {
            if (r < nv) {
                float v = fmaxf(a[r], 0.f);
                size_t rr = ((size_t)(b * 173 + o0 + r)) * 196 + tid;
                if (RES) v += res[rr];
                outp[rr] = v;
                if (!RES) aux[((size_t)b * 196 + tid) * 173 + o0 + r] = v;
                if (RES) vals[r][tid] = v;
            }
        }
    } else if (RES) {
#pragma unroll
        for (int r = 0; r < ROWS; ++r) vals[r][tid & 7] = vals[r][tid & 7]; // no-op
    }
    if (RES) {
        __syncthreads();
        int wv = tid >> 6, lane = tid & 63;
        for (int k = 0;; ++k) {
            int r = wv + 4 * k;
            if (r >= nv) break;
            float s = 0.f;
            for (int j = lane; j < 196; j += 64) s += vals[r][j];
            for (int sh = 32; sh; sh >>= 1) s += __shfl_xor(s, sh);
            if (lane == 0) aux[(size_t)b * 173 + o0 + r] = s;
        }
    }
}

// ---------------- CMSA attention (multi-row, writes A^T) ----------------
template <int ROWS>
__global__ void k_cmsa_att_t(const float* __restrict__ q, const float* __restrict__ qT,
                             float* __restrict__ AT) {
    __shared__ float colt[ROWS][176];
    __shared__ float sc[ROWS][200];
    const int i0 = blockIdx.x * ROWS, b = blockIdx.y;
    const int tid = threadIdx.x;
    for (int idx = tid; idx < ROWS * 173; idx += 256) {
        int r = idx / 173, c = idx - r * 173;
        colt[r][c] = qT[((size_t)b * 196 + i0 + r) * 173 + c];
    }
    __syncthreads();
    if (tid < 196) {
        float a[ROWS];
#pragma unroll
        for (int r = 0; r < ROWS; ++r) a[r] = 0.f;
        for (int c = 0; c < 173; ++c) {
            float qv = q[((size_t)(b * 173 + c)) * 196 + tid];
#pragma unroll
            for (int r = 0; r < ROWS; ++r) a[r] += colt[r][c] * qv;
        }
#pragma unroll
        for (int r = 0; r < ROWS; ++r) sc[r][tid] = a[r];
    }
    __syncthreads();
    int wv = tid >> 6, lane = tid & 63;
    for (int k = 0;; ++k) {
        int r = wv + 4 * k;
        if (r >= ROWS) break;
        softseg(&sc[r][0], 196, lane);
    }
    __syncthreads();
    for (int idx = tid; idx < ROWS * 196; idx += 256) {
        int r = idx / 196, j = idx - r * 196;
        AT[((size_t)b * 196 + j) * 196 + i0 + r] = sc[r][j];
    }
}

// ---------------- CMSA apply (multi-row) ----------------
template <int ROWS>
__global__ void k_cmsa_apply_t(const float* __restrict__ AT, const float* __restrict__ q,
                               float* __restrict__ fea) {
    __shared__ float qsr[ROWS][196];
    const int c0 = blockIdx.x * ROWS, b = blockIdx.y;
    const int tid = threadIdx.x;
    const int nv = (173 - c0 < ROWS) ? (173 - c0) : ROWS;
    for (int idx = tid; idx < nv * 196; idx += 256) {
        int r = idx / 196, n = idx - r * 196;
        qsr[r][n] = q[((size_t)(b * 173 + c0 + r)) * 196 + n];
    }
    __syncthreads();
    if (tid < 196) {
        float a[ROWS];
#pragma unroll
        for (int r = 0; r < ROWS; ++r) a[r] = 0.f;
        const float* at = AT + (size_t)b * 196 * 196 + tid;
        for (int j = 0; j < 196; ++j) {
            float av = at[(size_t)j * 196];
#pragma unroll
            for (int r = 0; r < ROWS; ++r) a[r] += av * qsr[r][j];
        }
#pragma unroll
        for (int r = 0; r < ROWS; ++r)
            if (r < nv) fea[((size_t)(b * 173 + c0 + r)) * 196 + tid] = a[r];
    }
}

// ---------------- final classifier ----------------
__global__ void k_finale(const float* __restrict__ toh, const float* __restrict__ tnm,
                         const float* __restrict__ rowsum, const float* __restrict__ cls_w,
                         const float* __restrict__ cls_b, float* __restrict__ out) {
    int b = blockIdx.x;
    __shared__ float r1[4], r2[4];
    int tid = threadIdx.x;
    float a = (tid < 196) ? toh[b * 196 + tid] : 0.f;
    float c = (tid < 196) ? tnm[b * 196 + tid] : 0.f;
    for (int sh = 32; sh; sh >>= 1) { a += __shfl_xor(a, sh); c += __shfl_xor(c, sh); }
    if ((tid & 63) == 0) { r1[tid >> 6] = a; r2[tid >> 6] = c; }
    __syncthreads();
    if (tid < 2) {
        float soh = r1[0] + r1[1] + r1[2] + r1[3];
        float snm = r2[0] + r2[1] + r2[2] + r2[3];
        const float* wrow = &cls_w[tid * 218];
        float acc = cls_b[tid];
        float w1 = 0.f, w2 = 0.f;
        for (int k = 0; k < 30; ++k) w1 += wrow[k];
        for (int k = 30; k < 45; ++k) w2 += wrow[k];
        acc += soh * w1 + snm * w2;
        for (int k = 0; k < 173; ++k) acc += wrow[45 + k] * rowsum[(size_t)b * 173 + k];
        out[b * 2 + tid] = acc;
    }
}

// ---------------------------------------------------------------------------
extern "C" void kernel_launch(void* const* d_in, const int* in_sizes, int n_in,
                              void* d_out, int out_size, void* d_ws, size_t ws_size,
                              hipStream_t stream) {
    const float* x      = (const float*)d_in[0];
    const float* oneHot = (const float*)d_in[1];
    const float* num    = (const float*)d_in[2];
    const float* c1_w1  = (const float*)d_in[3];
    const float* c1_g1  = (const float*)d_in[5];
    const float* c1_be1 = (const float*)d_in[6];
    const float* c1_w2  = (const float*)d_in[7];
    const float* c1_g2  = (const float*)d_in[9];
    const float* c1_be2 = (const float*)d_in[10];
    const float* oh_w   = (const float*)d_in[11];
    const float* oh_b   = (const float*)d_in[12];
    const float* oh_g   = (const float*)d_in[13];
    const float* oh_be  = (const float*)d_in[14];
    const float* nm_w   = (const float*)d_in[15];
    const float* nm_b   = (const float*)d_in[16];
    const float* nm_g   = (const float*)d_in[17];
    const float* nm_be  = (const float*)d_in[18];
    const float* gm1_w  = (const float*)d_in[19];
    const float* gm1_b  = (const float*)d_in[20];
    const float* gm2_w  = (const float*)d_in[21];
    const float* gm2_b  = (const float*)d_in[22];
    const float* ln1_g  = (const float*)d_in[23];
    const float* ln1_b  = (const float*)d_in[24];
    const float* ln2_g  = (const float*)d_in[25];
    const float* ln2_b  = (const float*)d_in[26];
    const float* e1_w   = (const float*)d_in[27];
    const float* e1_b   = (const float*)d_in[28];
    const float* e2_w   = (const float*)d_in[29];
    const float* e2_b   = (const float*)d_in[30];
    const float* f1_w   = (const float*)d_in[31];
    const float* f1_b   = (const float*)d_in[32];
    const float* f2_w   = (const float*)d_in[33];
    const float* f2_b   = (const float*)d_in[34];
    const float* f3_w   = (const float*)d_in[35];
    const float* f3_b   = (const float*)d_in[36];
    const float* f4_w   = (const float*)d_in[37];
    const float* f4_b   = (const float*)d_in[38];
    const float* cm_w   = (const float*)d_in[39];
    const float* cm_b   = (const float*)d_in[40];
    const float* cmf_w  = (const float*)d_in[41];
    const float* cmf_b  = (const float*)d_in[42];
    const float* cls_w  = (const float*)d_in[43];
    const float* cls_b  = (const float*)d_in[44];
    float* out = (float*)d_out;
    float* W = (float*)d_ws;

    const size_t L = 802816;
    const size_t T = 282240;
    const size_t F3 = 1085056;
    const size_t S2 = 1229312;
    const size_t o_A    = 0;
    const size_t o_B    = L;
    const size_t o_C    = 2 * L;
    const size_t o_part = 3 * L;
    const size_t o_iq   = 3 * L;
    const size_t o_tq   = 4 * L;
    const size_t o_t1   = 4 * L + T;
    const size_t o_t3   = 4 * L + 2 * T;
    const size_t o_ln2  = 4 * L + 3 * T;
    const size_t o_toh  = 4 * L + 4 * T;
    const size_t o_tnm  = o_toh + 6272;
    const size_t o_st   = o_tnm + 6272;
    const size_t o_wT   = o_st + 1024;
    const size_t o_feat = o_wT + 8 * 38416;
    const size_t o_q    = o_feat + F3;
    const size_t o_fea  = o_q + F3;
    const size_t o_Acm  = o_fea + F3;
    const size_t o_d1   = o_Acm;
    const size_t o_d2   = o_Acm + 524288;
    const size_t o_xt1 = 9 * L;
    const size_t o_xt2 = o_xt1 + 1091584;
    const size_t o_wp1 = o_xt2 + 452608;
    const size_t o_wp2 = o_wp1 + 552960;
    const size_t o_tr  = 9543680;
    const size_t o_rs  = o_tr + F3;

    float* part = W + o_part;
    unsigned short* xt1 = (unsigned short*)(W + o_xt1);
    unsigned short* xt2 = (unsigned short*)(W + o_xt2);
    unsigned short* wp1 = (unsigned short*)(W + o_wp1);
    unsigned short* wp2 = (unsigned short*)(W + o_wp2);
    float* gm1T = W + o_wT + 0 * 38416;
    float* gm2T = W + o_wT + 1 * 38416;
    float* e1T  = W + o_wT + 2 * 38416;
    float* e2T  = W + o_wT + 3 * 38416;
    float* f1T  = W + o_wT + 4 * 38416;
    float* f2T  = W + o_wT + 5 * 38416;
    float* f3T  = W + o_wT + 6 * 38416;
    float* f4T  = W + o_wT + 7 * 38416;

    hipFuncSetAttribute((const void*)&k_convmfma<320, 328, 45, 10>,
                        hipFuncAttributeMaxDynamicSharedMemorySize, 208 * 328 * 2);
    hipFuncSetAttribute((const void*)&k_convmfma<128, 136, 18, 4>,
                        hipFuncAttributeMaxDynamicSharedMemorySize, 208 * 136 * 2);

    // ---- conv prep ----
    k_wpack<<<(27 * 128 * 40 + 255) / 256, 256, 0, stream>>>(c1_w1, wp1, 320);
    k_wpack<<<(27 * 128 * 16 + 255) / 256, 256, 0, stream>>>(c1_w2, wp2, 128);
    k_xt<<<dim3((208 * 164 + 255) / 256, 32), 256, 0, stream>>>(x, xt1, 320, 328);

    // ---- conv1 ----
    k_convmfma<320, 328, 45, 10><<<dim3(6, 32), 256, 208 * 328 * 2, stream>>>(xt1, wp1, part);
    k_reduce6<<<3136, 256, 0, stream>>>(part, W + o_A, 802816);
    k_bn_stats<<<128, 256, 0, stream>>>(W + o_A, W + o_st, 128);
    k_bn_apply_relu<<<4096, 256, 0, stream>>>(W + o_A, W + o_st, c1_g1, c1_be1, nullptr, 128);

    // ---- conv2 ----
    k_xt<<<dim3((208 * 68 + 255) / 256, 32), 256, 0, stream>>>(W + o_A, xt2, 128, 136);
    k_convmfma<128, 136, 18, 4><<<dim3(6, 32), 256, 208 * 136 * 2, stream>>>(xt2, wp2, part);
    k_reduce6<<<3136, 256, 0, stream>>>(part, W + o_B, 802816);
    k_bn_stats<<<128, 256, 0, stream>>>(W + o_B, W + o_st + 512, 128);
    k_bn_apply_relu<<<4096, 256, 0, stream>>>(W + o_B, W + o_st + 512, c1_g2, c1_be2,
                                              W + o_tr, 128);

    // ---- weight transposes ----
    P8 p8;
    p8.p[0] = gm1_w; p8.p[1] = gm2_w; p8.p[2] = e1_w; p8.p[3] = e2_w;
    p8.p[4] = f1_w;  p8.p[5] = f2_w;  p8.p[6] = f3_w; p8.p[7] = f4_w;
    k_transpose8<<<dim3(196, 8), 256, 0, stream>>>(p8, W + o_wT);

    // ---- catnum / text ----
    k_catnum<<<196, 64, 0, stream>>>(oneHot, 24, oh_w, oh_b, oh_g, oh_be, W + o_toh);
    k_catnum<<<196, 64, 0, stream>>>(num, 11, nm_w, nm_b, nm_g, nm_be, W + o_tnm);
    k_textbuild<<<32 * 45, 256, 0, stream>>>(W + o_toh, W + o_tnm, W + o_t1, W + o_tr + L);

    // ---- GCN img ----
    k_gcn_dist_t<128, 8><<<dim3(16, 32), 256, 0, stream>>>(W + o_B, W + o_tr, W + o_d1);
    k_gcn_spmmfin_t<128, 8><<<dim3(16, 32), 256, 0, stream>>>(W + o_d1, W + o_B, gm1T,
                                                              gm1_b, W + o_C);
    // ---- GCN text ----
    k_gcn_dist_t<45, 5><<<dim3(9, 32), 256, 0, stream>>>(W + o_t1, W + o_tr + L, W + o_d2);
    k_gcn_spmmfin_t<45, 5><<<dim3(9, 32), 256, 0, stream>>>(W + o_d2, W + o_t1, gm2T,
                                                            gm2_b, W + o_t3);

    // ---- LN + q projections ----
    k_lnlin_t<128, 8><<<dim3(16, 32), 256, 0, stream>>>(W + o_C, ln1_g, ln1_b, e1T, e1_b,
                                                        W + o_B, W + o_iq, W + o_tr);
    k_lnlin_t<45, 5><<<dim3(9, 32), 256, 0, stream>>>(W + o_t3, ln2_g, ln2_b, e2T, e2_b,
                                                      W + o_ln2, W + o_tq, W + o_tr + L);

    // ---- cross-attention -> feat ----
    k_attrow_t<8, 128, 45><<<dim3(16, 32), 256, 0, stream>>>(
        W + o_iq, W + o_tr, W + o_tq, W + o_tr + L,
        f1T, f1_b, f3T, f3_b, W + o_B, W + o_C, W + o_feat, 0);
    k_attrow_t<5, 45, 128><<<dim3(9, 32), 256, 0, stream>>>(
        W + o_tq, W + o_tr + L, W + o_iq, W + o_tr,
        f2T, f2_b, f4T, f4_b, W + o_ln2, W + o_t3, W + o_feat, 128);

    // ---- CMSA ----
    k_conv1x1_t<0, 8><<<dim3(22, 32), 256, 0, stream>>>(W + o_feat, cm_w, cm_b, nullptr,
                                                        W + o_q, W + o_tr);
    k_cmsa_att_t<7><<<dim3(28, 32), 256, 0, stream>>>(W + o_q, W + o_tr, W + o_Acm);
    k_cmsa_apply_t<8><<<dim3(22, 32), 256, 0, stream>>>(W + o_Acm, W + o_q, W + o_fea);
    k_conv1x1_t<1, 8><<<dim3(22, 32), 256, 0, stream>>>(W + o_fea, cmf_w, cmf_b, W + o_feat,
                                                        W + o_q, W + o_rs);

    // ---- final classifier ----
    k_finale<<<32, 256, 0, stream>>>(W + o_toh, W + o_tnm, W + o_rs, cls_w, cls_b, out);
}

// Round 8
// 559.717 us; speedup vs baseline: 4.2912x; 1.0832x over previous
//
#include <hip/hip_runtime.h>
#include <hip/hip_bf16.h>

// ---------------------------------------------------------------------------
// mv3Dunet_down_text_cmsa forward. Round 8: MFMA convs + multi-row tail with
// TLP restored (ROWS=4/3 -> >=1024-block grids), de-diverged attention score
// phase, unroll-4 streaming loops for ILP.
// ---------------------------------------------------------------------------

using bf16x8 = __attribute__((ext_vector_type(8))) short;
using f32x4  = __attribute__((ext_vector_type(4))) float;

__device__ __forceinline__ unsigned short f2bf(float f) {
    unsigned int u = __float_as_uint(f);
    u += 0x7FFFu + ((u >> 16) & 1u);
    return (unsigned short)(u >> 16);
}

// in-place softmax over s[0..len) using one wave's 64 lanes
__device__ __forceinline__ void softseg(float* s, int len, int lane) {
    float m = -3.4e38f;
    for (int j = lane; j < len; j += 64) m = fmaxf(m, s[j]);
    for (int sh = 32; sh; sh >>= 1) m = fmaxf(m, __shfl_xor(m, sh));
    float sum = 0.f;
    for (int j = lane; j < len; j += 64) { float e = expf(s[j] - m); s[j] = e; sum += e; }
    for (int sh = 32; sh; sh >>= 1) sum += __shfl_xor(sum, sh);
    float inv = 1.f / sum;
    for (int j = lane; j < len; j += 64) s[j] *= inv;
}

// ---------------- X transpose + bf16 cast ----------------
__global__ void k_xt(const float* __restrict__ x, unsigned short* __restrict__ xt,
                     int IC, int ICPAD) {
    int b = blockIdx.y;
    int halfpad = ICPAD >> 1;
    int idx = blockIdx.x * 256 + threadIdx.x;
    if (idx >= 208 * halfpad) return;
    int s = idx / halfpad, icp = idx - s * halfpad;
    int ic = icp * 2;
    unsigned int lo = 0, hi = 0;
    if (s < 196 && ic < IC)     lo = f2bf(x[((size_t)b * IC + ic) * 196 + s]);
    if (s < 196 && ic + 1 < IC) hi = f2bf(x[((size_t)b * IC + ic + 1) * 196 + s]);
    ((unsigned int*)xt)[(size_t)b * 208 * halfpad + idx] = lo | (hi << 16);
}

// ---------------- weight pack ----------------
__global__ void k_wpack(const float* __restrict__ w, unsigned short* __restrict__ wp,
                        int IC) {
    int nc = IC >> 3;
    int idx = blockIdx.x * 256 + threadIdx.x;
    if (idx >= 27 * 128 * nc) return;
    int c = idx % nc; int r = idx / nc; int oc = r & 127; int t = r >> 7;
    const float* ws = w + ((size_t)oc * IC + c * 8) * 27 + t;
    unsigned int o0 = f2bf(ws[0])   | ((unsigned int)f2bf(ws[27])  << 16);
    unsigned int o1 = f2bf(ws[54])  | ((unsigned int)f2bf(ws[81])  << 16);
    unsigned int o2 = f2bf(ws[108]) | ((unsigned int)f2bf(ws[135]) << 16);
    unsigned int o3 = f2bf(ws[162]) | ((unsigned int)f2bf(ws[189]) << 16);
    uint4 v; v.x = o0; v.y = o1; v.z = o2; v.w = o3;
    ((uint4*)wp)[idx] = v;
}

// ---------------- MFMA conv: 27 shifted GEMMs ----------------
template <int IC, int ICPAD, int NU, int KKPT>
__global__ __launch_bounds__(256, 1) void k_convmfma(
    const unsigned short* __restrict__ xt, const unsigned short* __restrict__ wp,
    float* __restrict__ part) {
    extern __shared__ char smem_c[];
    const int tid = threadIdx.x;
    const int g = blockIdx.x, b = blockIdx.y;
    {
        const bf16x8* s8 = (const bf16x8*)(xt + (size_t)b * 208 * ICPAD);
        bf16x8* d8 = (bf16x8*)smem_c;
        for (int c = tid; c < 208 * ICPAD / 8; c += 256) d8[c] = s8[c];
    }
    __syncthreads();
    const int lane = tid & 63;
    const int wv = tid >> 6;
    const int a = lane & 15, kg = lane >> 4;
    int md[4], mh[4], mw[4];
#pragma unroll
    for (int i = 0; i < 4; ++i) {
        int m = (3 * wv + i) * 16 + a;
        md[i] = m / 49; int rr = m - md[i] * 49;
        mh[i] = rr / 7; mw[i] = rr - mh[i] * 7;
    }
    f32x4 acc[4][8];
#pragma unroll
    for (int i = 0; i < 4; ++i)
#pragma unroll
        for (int nt = 0; nt < 8; ++nt) acc[i][nt] = (f32x4){0.f, 0.f, 0.f, 0.f};
    const bf16x8 zv = {0, 0, 0, 0, 0, 0, 0, 0};
    int rsrc[4]; bool ok[4];
    int tcur = -1;
    for (int u = g * NU; u < (g + 1) * NU; ++u) {
        int t = u / KKPT, kk = u - t * KKPT;
        if (t != tcur) {
            tcur = t;
            int kd = t / 9, kh = (t / 3) % 3, kw = t % 3;
#pragma unroll
            for (int i = 0; i < 4; ++i) {
                int d2 = md[i] + kd - 1, h2 = mh[i] + kh - 1, w2 = mw[i] + kw - 1;
                ok[i] = ((unsigned)d2 < 4u) & ((unsigned)h2 < 7u) & ((unsigned)w2 < 7u);
                rsrc[i] = ok[i] ? (d2 * 49 + h2 * 7 + w2) : 0;
            }
        }
        int kb = kk * 32 + kg * 8;
        bf16x8 A[4];
#pragma unroll
        for (int i = 0; i < 4; ++i) {
            bf16x8 v = *(const bf16x8*)(smem_c + ((size_t)rsrc[i] * ICPAD + kb) * 2);
            A[i] = ok[i] ? v : zv;
        }
        const unsigned short* wrow = wp + ((size_t)t * 128 + a) * IC + kb;
#pragma unroll
        for (int nt = 0; nt < 8; ++nt) {
            bf16x8 B = *(const bf16x8*)(wrow + (size_t)nt * 16 * IC);
#pragma unroll
            for (int i = 0; i < 4; ++i)
                acc[i][nt] = __builtin_amdgcn_mfma_f32_16x16x32_bf16(A[i], B, acc[i][nt], 0, 0, 0);
        }
    }
    float* dst = part + ((size_t)g * 32 + b) * (128 * 196);
#pragma unroll
    for (int i = 0; i < 4; ++i) {
        int m0 = (3 * wv + i) * 16 + kg * 4;
        if (m0 < 196) {
#pragma unroll
            for (int nt = 0; nt < 8; ++nt) {
                int oc = nt * 16 + a;
                *(f32x4*)(dst + (size_t)oc * 196 + m0) = acc[i][nt];
            }
        }
    }
}

__global__ void k_reduce6(const float* __restrict__ part, float* __restrict__ y, int n) {
    int i = blockIdx.x * blockDim.x + threadIdx.x;
    if (i < n) {
        float s = 0.f;
#pragma unroll
        for (int g = 0; g < 6; ++g) s += part[(size_t)g * n + i];
        y[i] = s;
    }
}

// ---------------- transpose of 8 [196,196] matrices ----------------
struct P8 { const float* p[8]; };
__global__ void k_transpose8(P8 ws_in, float* __restrict__ wt) {
    int i = blockIdx.x, m = blockIdx.y;
    const float* w = ws_in.p[m];
    float* o = wt + (size_t)m * 38416;
    for (int t = threadIdx.x; t < 196; t += blockDim.x)
        o[(size_t)i * 196 + t] = w[(size_t)t * 196 + i];
}

// ---------------- BN ----------------
__global__ void k_bn_stats(const float* __restrict__ y, float* __restrict__ stats,
                           int C) {
    int ch = blockIdx.x; int tid = threadIdx.x;
    float s = 0.f, s2 = 0.f;
    for (int b = 0; b < 32; ++b) {
        const float* p = &y[(size_t)(b * C + ch) * 196];
        for (int i = tid; i < 196; i += 256) { float v = p[i]; s += v; s2 += v * v; }
    }
    __shared__ float r1[4], r2[4];
    for (int sh = 32; sh; sh >>= 1) { s += __shfl_xor(s, sh); s2 += __shfl_xor(s2, sh); }
    if ((tid & 63) == 0) { r1[tid >> 6] = s; r2[tid >> 6] = s2; }
    __syncthreads();
    if (tid == 0) {
        float S = r1[0] + r1[1] + r1[2] + r1[3];
        float S2 = r2[0] + r2[1] + r2[2] + r2[3];
        float m = S / 6272.f;
        float v = S2 / 6272.f - m * m;
        stats[2 * ch] = m;
        stats[2 * ch + 1] = rsqrtf(v + 1e-5f);
    }
}

__global__ void k_bn_apply_relu(float* __restrict__ y, const float* __restrict__ stats,
                                const float* __restrict__ g, const float* __restrict__ be,
                                float* __restrict__ fT, int C) {
    int idx = blockIdx.x;
    int ch = idx % C, b = idx / C;
    int s = threadIdx.x;
    if (s < 196) {
        float m = stats[2 * ch], r = stats[2 * ch + 1];
        float v = y[(size_t)idx * 196 + s];
        float o = fmaxf((v - m) * r * g[ch] + be[ch], 0.f);
        y[(size_t)idx * 196 + s] = o;
        if (fT) fT[((size_t)b * 196 + s) * C + ch] = o;
    }
}

// ---------------- catnum ----------------
__global__ void k_catnum(const float* __restrict__ inp, int A,
                         const float* __restrict__ w, const float* __restrict__ bias,
                         const float* __restrict__ g, const float* __restrict__ be,
                         float* __restrict__ outv) {
    int j = blockIdx.x;
    int lane = threadIdx.x;
    float v = 0.f;
    if (lane < 32) {
        v = bias[j];
        for (int k = 0; k < A; ++k) v += inp[lane * A + k] * w[j * A + k];
    }
    float s = (lane < 32) ? v : 0.f;
    float s2 = (lane < 32) ? v * v : 0.f;
    for (int m = 16; m; m >>= 1) { s += __shfl_xor(s, m, 32); s2 += __shfl_xor(s2, m, 32); }
    if (lane < 32) {
        float mean = s / 32.f;
        float var = s2 / 32.f - mean * mean;
        float rstd = rsqrtf(var + 1e-5f);
        float t = (v - mean) * rstd * g[j] + be[j];
        t = t / (1.f + expf(-t));
        outv[lane * 196 + j] = t;
    }
}

__global__ void k_textbuild(const float* __restrict__ toh, const float* __restrict__ tnm,
                            float* __restrict__ text, float* __restrict__ textT) {
    int idx = blockIdx.x;
    int b = idx / 45, c = idx - b * 45;
    int s = threadIdx.x;
    if (s < 196) {
        float v = (c < 30) ? toh[b * 196 + s] : tnm[b * 196 + s];
        text[(size_t)idx * 196 + s] = v;
        textT[((size_t)b * 196 + s) * 45 + c] = v;
    }
}

// ---------------- GCN dist (multi-row) ----------------
template <int C, int ROWS>
__global__ void k_gcn_dist_t(const float* __restrict__ f, const float* __restrict__ fT,
                             float* __restrict__ dist) {
    __shared__ float fi[ROWS][196];
    const int i0 = blockIdx.x * ROWS, b = blockIdx.y;
    const int tid = threadIdx.x;
    for (int idx = tid; idx < ROWS * 196; idx += 256) {
        int r = idx / 196, n = idx - r * 196;
        fi[r][n] = f[((size_t)(b * C + i0 + r)) * 196 + n];
    }
    __syncthreads();
    if (tid < C) {
        const float* ft = fT + (size_t)b * 196 * C + tid;
        float a[ROWS];
#pragma unroll
        for (int r = 0; r < ROWS; ++r) a[r] = 0.f;
#pragma unroll 4
        for (int n = 0; n < 196; ++n) {
            float v = ft[(size_t)n * C];
#pragma unroll
            for (int r = 0; r < ROWS; ++r) a[r] += fabsf(fi[r][n] - v);
        }
#pragma unroll
        for (int r = 0; r < ROWS; ++r)
            dist[((size_t)(b * C + i0 + r)) * C + tid] = expf(-a[r]);
    }
}

// ---------------- GCN spmm+fin (multi-row) ----------------
template <int C, int ROWS>
__global__ void k_gcn_spmmfin_t(const float* __restrict__ dist, const float* __restrict__ f,
                                const float* __restrict__ wt, const float* __restrict__ bias,
                                float* __restrict__ outp) {
    __shared__ float ds[ROWS][C];
    __shared__ float ts[ROWS][196];
    const int i0 = blockIdx.x * ROWS, b = blockIdx.y;
    const int tid = threadIdx.x;
    for (int idx = tid; idx < ROWS * C; idx += 256) {
        int r = idx / C, j = idx - r * C;
        ds[r][j] = dist[((size_t)(b * C + i0 + r)) * C + j];
    }
    __syncthreads();
    if (tid < 196) {
        float a[ROWS];
#pragma unroll
        for (int r = 0; r < ROWS; ++r) a[r] = 0.f;
#pragma unroll 4
        for (int j = 0; j < C; ++j) {
            float v = f[((size_t)b * C + j) * 196 + tid];
#pragma unroll
            for (int r = 0; r < ROWS; ++r) a[r] += ds[r][j] * v;
        }
#pragma unroll
        for (int r = 0; r < ROWS; ++r) ts[r][tid] = a[r];
    }
    __syncthreads();
    if (tid < 196) {
        float a[ROWS];
        float bi = bias[tid];
#pragma unroll
        for (int r = 0; r < ROWS; ++r) a[r] = bi;
#pragma unroll 4
        for (int n = 0; n < 196; ++n) {
            float wv = wt[(size_t)n * 196 + tid];
#pragma unroll
            for (int r = 0; r < ROWS; ++r) a[r] += ts[r][n] * wv;
        }
#pragma unroll
        for (int r = 0; r < ROWS; ++r) {
            size_t rr = ((size_t)(b * C + i0 + r)) * 196 + tid;
            outp[rr] = fmaxf(a[r], 0.f) + f[rr];
        }
    }
}

// ---------------- LN + relu(linear), multi-row, dual-layout q ----------------
template <int R, int ROWS>
__global__ void k_lnlin_t(const float* __restrict__ x, const float* __restrict__ g,
                          const float* __restrict__ be, const float* __restrict__ eT,
                          const float* __restrict__ eb, float* __restrict__ lnout,
                          float* __restrict__ qout, float* __restrict__ qT) {
    __shared__ float ls[ROWS][196];
    const int i0 = blockIdx.x * ROWS, b = blockIdx.y;
    const int tid = threadIdx.x;
    const int wv = tid >> 6, lane = tid & 63;
    for (int idx = tid; idx < ROWS * 196; idx += 256) {
        int r = idx / 196, n = idx - r * 196;
        ls[r][n] = x[((size_t)(b * R + i0 + r)) * 196 + n];
    }
    __syncthreads();
    for (int k = 0;; ++k) {
        int r = wv + 4 * k;
        if (r >= ROWS) break;
        float s = 0.f, s2 = 0.f;
        for (int j = lane; j < 196; j += 64) { float v = ls[r][j]; s += v; s2 += v * v; }
        for (int sh = 32; sh; sh >>= 1) { s += __shfl_xor(s, sh); s2 += __shfl_xor(s2, sh); }
        float mean = s / 196.f;
        float var = s2 / 196.f - mean * mean;
        float rstd = rsqrtf(var + 1e-6f);
        size_t rowo = ((size_t)(b * R + i0 + r)) * 196;
        for (int j = lane; j < 196; j += 64) {
            float l = (ls[r][j] - mean) * rstd * g[j] + be[j];
            ls[r][j] = l;
            lnout[rowo + j] = l;
        }
    }
    __syncthreads();
    if (tid < 196) {
        float a[ROWS];
        float bi = eb[tid];
#pragma unroll
        for (int r = 0; r < ROWS; ++r) a[r] = bi;
#pragma unroll 4
        for (int n = 0; n < 196; ++n) {
            float ev = eT[(size_t)n * 196 + tid];
#pragma unroll
            for (int r = 0; r < ROWS; ++r) a[r] += ls[r][n] * ev;
        }
#pragma unroll
        for (int r = 0; r < ROWS; ++r) {
            float q = fmaxf(a[r], 0.f);
            qout[((size_t)(b * R + i0 + r)) * 196 + tid] = q;
            qT[((size_t)b * 196 + tid) * R + i0 + r] = q;
        }
    }
}

// ---------------- fused cross-attention, multi-row, de-diverged ------------
template <int ROWS, int RA, int RB>
__global__ void k_attrow_t(const float* __restrict__ own, const float* __restrict__ ownT,
                           const float* __restrict__ oth, const float* __restrict__ othT,
                           const float* __restrict__ wAT, const float* __restrict__ bA,
                           const float* __restrict__ wBT, const float* __restrict__ bB,
                           const float* __restrict__ lnres, const float* __restrict__ res2,
                           float* __restrict__ feat, int cbase) {
    __shared__ float buf1[ROWS][196];      // qs -> fA
    __shared__ float sc[ROWS][176];        // scores -> probs (RA+RB=173)
    __shared__ float fB[ROWS][196];
    const int i0 = blockIdx.x * ROWS, b = blockIdx.y;
    const int tid = threadIdx.x;
    const int wv = tid >> 6, lane = tid & 63;
    const float* ownb = own + (size_t)b * RA * 196;
    const float* othb = oth + (size_t)b * RB * 196;
    for (int idx = tid; idx < ROWS * 196; idx += 256) {
        int r = idx / 196, n = idx - r * 196;
        buf1[r][n] = ownb[(size_t)(i0 + r) * 196 + n];
    }
    __syncthreads();
    // score phase: uniform loop, per-thread base/stride (no wave divergence)
    {
        const bool act = tid < RA + RB;
        const float* ptr = nullptr;
        int stride = 1;
        if (act) {
            if (tid < RA) { ptr = ownT + (size_t)b * 196 * RA + tid; stride = RA; }
            else          { ptr = othT + (size_t)b * 196 * RB + (tid - RA); stride = RB; }
        }
        if (act) {
            float a[ROWS];
#pragma unroll
            for (int r = 0; r < ROWS; ++r) a[r] = 0.f;
#pragma unroll 4
            for (int n = 0; n < 196; ++n) {
                float kv = ptr[(size_t)n * stride];
#pragma unroll
                for (int r = 0; r < ROWS; ++r) a[r] += buf1[r][n] * kv;
            }
#pragma unroll
            for (int r = 0; r < ROWS; ++r) sc[r][tid] = a[r];
        }
    }
    __syncthreads();
    for (int k = 0;; ++k) {
        int r = wv + 4 * k;
        if (r >= ROWS) break;
        softseg(&sc[r][0], RA, lane);
        softseg(&sc[r][RA], RB, lane);
    }
    __syncthreads();
    if (tid < 196) {
        float a[ROWS];
#pragma unroll
        for (int r = 0; r < ROWS; ++r) a[r] = 0.f;
#pragma unroll 4
        for (int j = 0; j < RA; ++j) {
            float v = ownb[(size_t)j * 196 + tid];
#pragma unroll
            for (int r = 0; r < ROWS; ++r) a[r] += sc[r][j] * v;
        }
        float c[ROWS];
#pragma unroll
        for (int r = 0; r < ROWS; ++r) c[r] = 0.f;
#pragma unroll 4
        for (int j = 0; j < RB; ++j) {
            float v = othb[(size_t)j * 196 + tid];
#pragma unroll
            for (int r = 0; r < ROWS; ++r) c[r] += sc[r][RA + j] * v;
        }
#pragma unroll
        for (int r = 0; r < ROWS; ++r) { buf1[r][tid] = a[r]; fB[r][tid] = c[r]; }
    }
    __syncthreads();
    if (tid < 196) {
        float a[ROWS];
        float bb = bA[tid] + bB[tid];
#pragma unroll
        for (int r = 0; r < ROWS; ++r) {
            size_t rr = ((size_t)(b * RA + i0 + r)) * 196 + tid;
            a[r] = bb + lnres[rr] + res2[rr];
        }
#pragma unroll 4
        for (int n = 0; n < 196; ++n) {
            float wa = wAT[(size_t)n * 196 + tid];
            float wb = wBT[(size_t)n * 196 + tid];
#pragma unroll
            for (int r = 0; r < ROWS; ++r) a[r] += buf1[r][n] * wa + fB[r][n] * wb;
        }
#pragma unroll
        for (int r = 0; r < ROWS; ++r)
            feat[((size_t)(b * 173 + cbase + i0 + r)) * 196 + tid] = a[r];
    }
}

// ---------------- 1x1 conv, multi-row; RES=0 writes qT, RES=1 res+rowsum ----
template <int RES, int ROWS>
__global__ void k_conv1x1_t(const float* __restrict__ x, const float* __restrict__ w,
                            const float* __restrict__ bias, const float* __restrict__ res,
                            float* __restrict__ outp, float* __restrict__ aux) {
    __shared__ float wsm[ROWS][173];
    __shared__ float vals[ROWS][200];
    const int o0 = blockIdx.x * ROWS, b = blockIdx.y;
    const int tid = threadIdx.x;
    const int nv = (173 - o0 < ROWS) ? (173 - o0) : ROWS;
    for (int idx = tid; idx < nv * 173; idx += 256) {
        int r = idx / 173, c = idx - r * 173;
        wsm[r][c] = w[(size_t)(o0 + r) * 173 + c];
    }
    __syncthreads();
    if (tid < 196) {
        float a[ROWS];
#pragma unroll
        for (int r = 0; r < ROWS; ++r) a[r] = (r < nv) ? bias[o0 + r] : 0.f;
#pragma unroll 4
        for (int c = 0; c < 173; ++c) {
            float xv = x[((size_t)(b * 173 + c)) * 196 + tid];
#pragma unroll
            for (int r = 0; r < ROWS; ++r) a[r] += wsm[r][c] * xv;
        }
#pragma unroll
        for (int r = 0; r < ROWS; ++r) {
            if (r < nv) {
                float v = fmaxf(a[r], 0.f);
                size_t rr = ((size_t)(b * 173 + o0 + r)) * 196 + tid;
                if (RES) v += res[rr];
                outp[rr] = v;
                if (!RES) aux[((size_t)b * 196 + tid) * 173 + o0 + r] = v;
                if (RES) vals[r][tid] = v;
            }
        }
    }
    if (RES) {
        __syncthreads();
        int wv = tid >> 6, lane = tid & 63;
        for (int k = 0;; ++k) {
            int r = wv + 4 * k;
            if (r >= nv) break;
            float s = 0.f;
            for (int j = lane; j < 196; j += 64) s += vals[r][j];
            for (int sh = 32; sh; sh >>= 1) s += __shfl_xor(s, sh);
            if (lane == 0) aux[(size_t)b * 173 + o0 + r] = s;
        }
    }
}

// ---------------- CMSA attention (multi-row, writes A^T) ----------------
template <int ROWS>
__global__ void k_cmsa_att_t(const float* __restrict__ q, const float* __restrict__ qT,
                             float* __restrict__ AT) {
    __shared__ float colt[ROWS][176];
    __shared__ float sc[ROWS][200];
    const int i0 = blockIdx.x * ROWS, b = blockIdx.y;
    const int tid = threadIdx.x;
    for (int idx = tid; idx < ROWS * 173; idx += 256) {
        int r = idx / 173, c = idx - r * 173;
        colt[r][c] = qT[((size_t)b * 196 + i0 + r) * 173 + c];
    }
    __syncthreads();
    if (tid < 196) {
        float a[ROWS];
#pragma unroll
        for (int r = 0; r < ROWS; ++r) a[r] = 0.f;
#pragma unroll 4
        for (int c = 0; c < 173; ++c) {
            float qv = q[((size_t)(b * 173 + c)) * 196 + tid];
#pragma unroll
            for (int r = 0; r < ROWS; ++r) a[r] += colt[r][c] * qv;
        }
#pragma unroll
        for (int r = 0; r < ROWS; ++r) sc[r][tid] = a[r];
    }
    __syncthreads();
    int wv = tid >> 6, lane = tid & 63;
    for (int k = 0;; ++k) {
        int r = wv + 4 * k;
        if (r >= ROWS) break;
        softseg(&sc[r][0], 196, lane);
    }
    __syncthreads();
    for (int idx = tid; idx < ROWS * 196; idx += 256) {
        int r = idx / 196, j = idx - r * 196;
        AT[((size_t)b * 196 + j) * 196 + i0 + r] = sc[r][j];
    }
}

// ---------------- CMSA apply (multi-row) ----------------
template <int ROWS>
__global__ void k_cmsa_apply_t(const float* __restrict__ AT, const float* __restrict__ q,
                               float* __restrict__ fea) {
    __shared__ float qsr[ROWS][196];
    const int c0 = blockIdx.x * ROWS, b = blockIdx.y;
    const int tid = threadIdx.x;
    const int nv = (173 - c0 < ROWS) ? (173 - c0) : ROWS;
    for (int idx = tid; idx < nv * 196; idx += 256) {
        int r = idx / 196, n = idx - r * 196;
        qsr[r][n] = q[((size_t)(b * 173 + c0 + r)) * 196 + n];
    }
    __syncthreads();
    if (tid < 196) {
        float a[ROWS];
#pragma unroll
        for (int r = 0; r < ROWS; ++r) a[r] = 0.f;
        const float* at = AT + (size_t)b * 196 * 196 + tid;
#pragma unroll 4
        for (int j = 0; j < 196; ++j) {
            float av = at[(size_t)j * 196];
#pragma unroll
            for (int r = 0; r < ROWS; ++r) a[r] += av * qsr[r][j];
        }
#pragma unroll
        for (int r = 0; r < ROWS; ++r)
            if (r < nv) fea[((size_t)(b * 173 + c0 + r)) * 196 + tid] = a[r];
    }
}

// ---------------- final classifier ----------------
__global__ void k_finale(const float* __restrict__ toh, const float* __restrict__ tnm,
                         const float* __restrict__ rowsum, const float* __restrict__ cls_w,
                         const float* __restrict__ cls_b, float* __restrict__ out) {
    int b = blockIdx.x;
    __shared__ float r1[4], r2[4];
    int tid = threadIdx.x;
    float a = (tid < 196) ? toh[b * 196 + tid] : 0.f;
    float c = (tid < 196) ? tnm[b * 196 + tid] : 0.f;
    for (int sh = 32; sh; sh >>= 1) { a += __shfl_xor(a, sh); c += __shfl_xor(c, sh); }
    if ((tid & 63) == 0) { r1[tid >> 6] = a; r2[tid >> 6] = c; }
    __syncthreads();
    if (tid < 2) {
        float soh = r1[0] + r1[1] + r1[2] + r1[3];
        float snm = r2[0] + r2[1] + r2[2] + r2[3];
        const float* wrow = &cls_w[tid * 218];
        float acc = cls_b[tid];
        float w1 = 0.f, w2 = 0.f;
        for (int k = 0; k < 30; ++k) w1 += wrow[k];
        for (int k = 30; k < 45; ++k) w2 += wrow[k];
        acc += soh * w1 + snm * w2;
        for (int k = 0; k < 173; ++k) acc += wrow[45 + k] * rowsum[(size_t)b * 173 + k];
        out[b * 2 + tid] = acc;
    }
}

// ---------------------------------------------------------------------------
extern "C" void kernel_launch(void* const* d_in, const int* in_sizes, int n_in,
                              void* d_out, int out_size, void* d_ws, size_t ws_size,
                              hipStream_t stream) {
    const float* x      = (const float*)d_in[0];
    const float* oneHot = (const float*)d_in[1];
    const float* num    = (const float*)d_in[2];
    const float* c1_w1  = (const float*)d_in[3];
    const float* c1_g1  = (const float*)d_in[5];
    const float* c1_be1 = (const float*)d_in[6];
    const float* c1_w2  = (const float*)d_in[7];
    const float* c1_g2  = (const float*)d_in[9];
    const float* c1_be2 = (const float*)d_in[10];
    const float* oh_w   = (const float*)d_in[11];
    const float* oh_b   = (const float*)d_in[12];
    const float* oh_g   = (const float*)d_in[13];
    const float* oh_be  = (const float*)d_in[14];
    const float* nm_w   = (const float*)d_in[15];
    const float* nm_b   = (const float*)d_in[16];
    const float* nm_g   = (const float*)d_in[17];
    const float* nm_be  = (const float*)d_in[18];
    const float* gm1_w  = (const float*)d_in[19];
    const float* gm1_b  = (const float*)d_in[20];
    const float* gm2_w  = (const float*)d_in[21];
    const float* gm2_b  = (const float*)d_in[22];
    const float* ln1_g  = (const float*)d_in[23];
    const float* ln1_b  = (const float*)d_in[24];
    const float* ln2_g  = (const float*)d_in[25];
    const float* ln2_b  = (const float*)d_in[26];
    const float* e1_w   = (const float*)d_in[27];
    const float* e1_b   = (const float*)d_in[28];
    const float* e2_w   = (const float*)d_in[29];
    const float* e2_b   = (const float*)d_in[30];
    const float* f1_w   = (const float*)d_in[31];
    const float* f1_b   = (const float*)d_in[32];
    const float* f2_w   = (const float*)d_in[33];
    const float* f2_b   = (const float*)d_in[34];
    const float* f3_w   = (const float*)d_in[35];
    const float* f3_b   = (const float*)d_in[36];
    const float* f4_w   = (const float*)d_in[37];
    const float* f4_b   = (const float*)d_in[38];
    const float* cm_w   = (const float*)d_in[39];
    const float* cm_b   = (const float*)d_in[40];
    const float* cmf_w  = (const float*)d_in[41];
    const float* cmf_b  = (const float*)d_in[42];
    const float* cls_w  = (const float*)d_in[43];
    const float* cls_b  = (const float*)d_in[44];
    float* out = (float*)d_out;
    float* W = (float*)d_ws;

    const size_t L = 802816;
    const size_t T = 282240;
    const size_t F3 = 1085056;
    const size_t S2 = 1229312;
    const size_t o_A    = 0;
    const size_t o_B    = L;
    const size_t o_C    = 2 * L;
    const size_t o_part = 3 * L;
    const size_t o_iq   = 3 * L;
    const size_t o_tq   = 4 * L;
    const size_t o_t1   = 4 * L + T;
    const size_t o_t3   = 4 * L + 2 * T;
    const size_t o_ln2  = 4 * L + 3 * T;
    const size_t o_toh  = 4 * L + 4 * T;
    const size_t o_tnm  = o_toh + 6272;
    const size_t o_st   = o_tnm + 6272;
    const size_t o_wT   = o_st + 1024;
    const size_t o_feat = o_wT + 8 * 38416;
    const size_t o_q    = o_feat + F3;
    const size_t o_fea  = o_q + F3;
    const size_t o_Acm  = o_fea + F3;
    const size_t o_d1   = o_Acm;
    const size_t o_d2   = o_Acm + 524288;
    const size_t o_xt1 = 9 * L;
    const size_t o_xt2 = o_xt1 + 1091584;
    const size_t o_wp1 = o_xt2 + 452608;
    const size_t o_wp2 = o_wp1 + 552960;
    const size_t o_tr  = 9543680;
    const size_t o_rs  = o_tr + F3;

    float* part = W + o_part;
    unsigned short* xt1 = (unsigned short*)(W + o_xt1);
    unsigned short* xt2 = (unsigned short*)(W + o_xt2);
    unsigned short* wp1 = (unsigned short*)(W + o_wp1);
    unsigned short* wp2 = (unsigned short*)(W + o_wp2);
    float* gm1T = W + o_wT + 0 * 38416;
    float* gm2T = W + o_wT + 1 * 38416;
    float* e1T  = W + o_wT + 2 * 38416;
    float* e2T  = W + o_wT + 3 * 38416;
    float* f1T  = W + o_wT + 4 * 38416;
    float* f2T  = W + o_wT + 5 * 38416;
    float* f3T  = W + o_wT + 6 * 38416;
    float* f4T  = W + o_wT + 7 * 38416;

    hipFuncSetAttribute((const void*)&k_convmfma<320, 328, 45, 10>,
                        hipFuncAttributeMaxDynamicSharedMemorySize, 208 * 328 * 2);
    hipFuncSetAttribute((const void*)&k_convmfma<128, 136, 18, 4>,
                        hipFuncAttributeMaxDynamicSharedMemorySize, 208 * 136 * 2);

    // ---- conv prep ----
    k_wpack<<<(27 * 128 * 40 + 255) / 256, 256, 0, stream>>>(c1_w1, wp1, 320);
    k_wpack<<<(27 * 128 * 16 + 255) / 256, 256, 0, stream>>>(c1_w2, wp2, 128);
    k_xt<<<dim3((208 * 164 + 255) / 256, 32), 256, 0, stream>>>(x, xt1, 320, 328);

    // ---- conv1 ----
    k_convmfma<320, 328, 45, 10><<<dim3(6, 32), 256, 208 * 328 * 2, stream>>>(xt1, wp1, part);
    k_reduce6<<<3136, 256, 0, stream>>>(part, W + o_A, 802816);
    k_bn_stats<<<128, 256, 0, stream>>>(W + o_A, W + o_st, 128);
    k_bn_apply_relu<<<4096, 256, 0, stream>>>(W + o_A, W + o_st, c1_g1, c1_be1, nullptr, 128);

    // ---- conv2 ----
    k_xt<<<dim3((208 * 68 + 255) / 256, 32), 256, 0, stream>>>(W + o_A, xt2, 128, 136);
    k_convmfma<128, 136, 18, 4><<<dim3(6, 32), 256, 208 * 136 * 2, stream>>>(xt2, wp2, part);
    k_reduce6<<<3136, 256, 0, stream>>>(part, W + o_B, 802816);
    k_bn_stats<<<128, 256, 0, stream>>>(W + o_B, W + o_st + 512, 128);
    k_bn_apply_relu<<<4096, 256, 0, stream>>>(W + o_B, W + o_st + 512, c1_g2, c1_be2,
                                              W + o_tr, 128);

    // ---- weight transposes ----
    P8 p8;
    p8.p[0] = gm1_w; p8.p[1] = gm2_w; p8.p[2] = e1_w; p8.p[3] = e2_w;
    p8.p[4] = f1_w;  p8.p[5] = f2_w;  p8.p[6] = f3_w; p8.p[7] = f4_w;
    k_transpose8<<<dim3(196, 8), 256, 0, stream>>>(p8, W + o_wT);

    // ---- catnum / text ----
    k_catnum<<<196, 64, 0, stream>>>(oneHot, 24, oh_w, oh_b, oh_g, oh_be, W + o_toh);
    k_catnum<<<196, 64, 0, stream>>>(num, 11, nm_w, nm_b, nm_g, nm_be, W + o_tnm);
    k_textbuild<<<32 * 45, 256, 0, stream>>>(W + o_toh, W + o_tnm, W + o_t1, W + o_tr + L);

    // ---- GCN img ----
    k_gcn_dist_t<128, 4><<<dim3(32, 32), 256, 0, stream>>>(W + o_B, W + o_tr, W + o_d1);
    k_gcn_spmmfin_t<128, 4><<<dim3(32, 32), 256, 0, stream>>>(W + o_d1, W + o_B, gm1T,
                                                              gm1_b, W + o_C);
    // ---- GCN text ----
    k_gcn_dist_t<45, 3><<<dim3(15, 32), 256, 0, stream>>>(W + o_t1, W + o_tr + L, W + o_d2);
    k_gcn_spmmfin_t<45, 3><<<dim3(15, 32), 256, 0, stream>>>(W + o_d2, W + o_t1, gm2T,
                                                             gm2_b, W + o_t3);

    // ---- LN + q projections ----
    k_lnlin_t<128, 4><<<dim3(32, 32), 256, 0, stream>>>(W + o_C, ln1_g, ln1_b, e1T, e1_b,
                                                        W + o_B, W + o_iq, W + o_tr);
    k_lnlin_t<45, 3><<<dim3(15, 32), 256, 0, stream>>>(W + o_t3, ln2_g, ln2_b, e2T, e2_b,
                                                       W + o_ln2, W + o_tq, W + o_tr + L);

    // ---- cross-attention -> feat ----
    k_attrow_t<4, 128, 45><<<dim3(32, 32), 256, 0, stream>>>(
        W + o_iq, W + o_tr, W + o_tq, W + o_tr + L,
        f1T, f1_b, f3T, f3_b, W + o_B, W + o_C, W + o_feat, 0);
    k_attrow_t<3, 45, 128><<<dim3(15, 32), 256, 0, stream>>>(
        W + o_tq, W + o_tr + L, W + o_iq, W + o_tr,
        f2T, f2_b, f4T, f4_b, W + o_ln2, W + o_t3, W + o_feat, 128);

    // ---- CMSA ----
    k_conv1x1_t<0, 4><<<dim3(44, 32), 256, 0, stream>>>(W + o_feat, cm_w, cm_b, nullptr,
                                                        W + o_q, W + o_tr);
    k_cmsa_att_t<4><<<dim3(49, 32), 256, 0, stream>>>(W + o_q, W + o_tr, W + o_Acm);
    k_cmsa_apply_t<4><<<dim3(44, 32), 256, 0, stream>>>(W + o_Acm, W + o_q, W + o_fea);
    k_conv1x1_t<1, 4><<<dim3(44, 32), 256, 0, stream>>>(W + o_fea, cmf_w, cmf_b, W + o_feat,
                                                        W + o_q, W + o_rs);

    // ---- final classifier ----
    k_finale<<<32, 256, 0, stream>>>(W + o_toh, W + o_tnm, W + o_rs, cls_w, cls_b, out);
}